// Round 13
// baseline (389.068 us; speedup 1.0000x reference)
//
#include <hip/hip_runtime.h>

#define WF 257
#define LAM 0.01f
#define ROWH 540
#define LPH(i) ((i) + (((i)>>6)<<2))

#define WSYNC() do { asm volatile("" ::: "memory"); __builtin_amdgcn_wave_barrier(); asm volatile("" ::: "memory"); } while(0)

typedef __attribute__((ext_vector_type(8))) short short8;
typedef __attribute__((ext_vector_type(4))) float f32x4;
typedef __attribute__((ext_vector_type(2))) __fp16 h2v;
typedef __attribute__((ext_vector_type(8))) __fp16 h8;

union UH8 { uint4 u; h8 h; };

__device__ __forceinline__ ushort f2bf(float f){
    unsigned u = __float_as_uint(f);
    unsigned r = (u + 0x7fffu + ((u >> 16) & 1u)) >> 16;
    return (ushort)r;
}
__device__ __forceinline__ float bf2f(ushort u){ return __uint_as_float((uint)u << 16); }
__device__ __forceinline__ uint packbf(float a, float b){
    return (uint)f2bf(a) | ((uint)f2bf(b) << 16);
}
__device__ __forceinline__ float2 unpackbf(uint u){
    return make_float2(__uint_as_float(u << 16), __uint_as_float(u & 0xffff0000u));
}
__device__ __forceinline__ uint packh(float a, float b){
    h2v h = __builtin_amdgcn_cvt_pkrtz(a, b);
    return *(uint*)&h;
}
__device__ __forceinline__ uint packh2(float2 v){ return packh(v.x, v.y); }
__device__ __forceinline__ float2 unph(uint u){
    h2v h = *(h2v*)&u;
    return make_float2((float)h[0], (float)h[1]);
}

__device__ __forceinline__ float2 cmul(float2 a, float2 b){
    return make_float2(a.x*b.x - a.y*b.y, a.x*b.y + a.y*b.x);
}
__device__ __forceinline__ float2 cadd(float2 a, float2 b){ return make_float2(a.x+b.x, a.y+b.y); }
__device__ __forceinline__ float2 csub(float2 a, float2 b){ return make_float2(a.x-b.x, a.y-b.y); }

template<int NTHREADS>
__device__ __forceinline__ void ld_tw(float2* tw, const float2* __restrict__ twg, int tid){
    for (int t = tid; t < 256; t += NTHREADS)
        ((float4*)tw)[t] = ((const float4*)twg)[t];
}

template<bool INV>
__device__ __forceinline__ float2 twz(const float2* tw, int idx){
    float2 w = tw[idx];
    if (INV) w.y = -w.y;
    return w;
}

template<bool INV>
__device__ __forceinline__ void dft8(float2 v[8]) {
    const float R = 0.70710678118654752f;
    float2 y0=v[0], y1=v[4], y2=v[2], y3=v[6], y4=v[1], y5=v[5], y6=v[3], y7=v[7];
    float2 t;
    t=y1; y1=csub(y0,t); y0=cadd(y0,t);
    t=y3; y3=csub(y2,t); y2=cadd(y2,t);
    t=y5; y5=csub(y4,t); y4=cadd(y4,t);
    t=y7; y7=csub(y6,t); y6=cadd(y6,t);
    t=y2; y2=csub(y0,t); y0=cadd(y0,t);
    t = INV ? make_float2(-y3.y, y3.x) : make_float2(y3.y, -y3.x);
    y3=csub(y1,t); y1=cadd(y1,t);
    t=y6; y6=csub(y4,t); y4=cadd(y4,t);
    t = INV ? make_float2(-y7.y, y7.x) : make_float2(y7.y, -y7.x);
    y7=csub(y5,t); y5=cadd(y5,t);
    t=y4; y4=csub(y0,t); y0=cadd(y0,t);
    { float2 w8 = INV ? make_float2(R, R) : make_float2(R,-R);
      t=cmul(y5,w8); y5=csub(y1,t); y1=cadd(y1,t); }
    t = INV ? make_float2(-y6.y, y6.x) : make_float2(y6.y, -y6.x);
    y6=csub(y2,t); y2=cadd(y2,t);
    { float2 w8 = INV ? make_float2(-R, R) : make_float2(-R,-R);
      t=cmul(y7,w8); y7=csub(y3,t); y3=cadd(y3,t); }
    v[0]=y0; v[1]=y1; v[2]=y2; v[3]=y3; v[4]=y4; v[5]=y5; v[6]=y6; v[7]=y7;
}

__device__ __forceinline__ void oct_write(uint* drow, int l, const float2 v[8]){
    uint* p = drow + LPH(8*l);
    *(uint4*)p       = make_uint4(packh2(v[0]), packh2(v[1]), packh2(v[2]), packh2(v[3]));
    *(uint4*)(p + 4) = make_uint4(packh2(v[4]), packh2(v[5]), packh2(v[6]), packh2(v[7]));
}

__device__ __forceinline__ void oct_gather(const uint* drow, int o0, float2 v[8]){
    const uint* b = drow + LPH(o0);
    #pragma unroll
    for (int q = 0; q < 8; ++q) v[q] = unph(b[68*q]);
}

template<bool INV>
__device__ __forceinline__ void fft_wave12(uint* drow, const float2* tw, int l)
{
    WSYNC();
    {
        int a = l&7, m = l>>3;
        uint* b = drow + 68*m + a;
        float2 v[8];
        v[0] = unph(b[0]);
        #pragma unroll
        for (int j = 1; j < 8; ++j)
            v[j] = cmul(unph(b[8*j]), twz<INV>(tw, 8*a*j));
        dft8<INV>(v);
        #pragma unroll
        for (int j = 0; j < 8; ++j) b[8*j] = packh2(v[j]);
    }
    WSYNC();
    {
        uint* b = drow + l;
        float2 v[8];
        v[0] = unph(b[0]);
        #pragma unroll
        for (int q = 1; q < 8; ++q)
            v[q] = cmul(unph(b[68*q]), twz<INV>(tw, (l*q)&511));
        dft8<INV>(v);
        #pragma unroll
        for (int q = 0; q < 8; ++q) b[68*q] = packh2(v[q]);
    }
    WSYNC();
}

__global__ void k_twiddle(float2* __restrict__ twg){
    int t = blockIdx.x*256 + threadIdx.x;
    if (t < 512) {
        float s, c;
        sincosf((float)t * (-6.2831853071795864769f/512.0f), &s, &c);
        twg[t] = make_float2(c, s);
    }
}

__device__ __forceinline__ float2 twf(int idx){
    float s, c;
    sincosf((float)(idx & 511) * (-6.2831853071795864769f/512.0f), &s, &c);
    return make_float2(c, s);
}

// precompute all MFMA twiddle A-fragments (block-invariant; values verbatim from R11 in-kernel build)
__global__ void k_mfrag(uint4* __restrict__ fA, uint4* __restrict__ fB,
                        uint4* __restrict__ fG, uint4* __restrict__ fC)
{
    const int lane = threadIdx.x;
    const int l15 = lane & 15;
    const int kb = (lane >> 4) * 8;
    for (int mt = 0; mt < 2; ++mt) {
        const int m = mt*16 + l15;
        uint ur[4], ui[4], un[4];
        for (int p = 0; p < 4; ++p) {
            float2 t0 = twf(16*m*(kb + 2*p));
            float2 t1 = twf(16*m*(kb + 2*p+1));
            ur[p] = packh(t0.x, t1.x);
            ui[p] = packh(t0.y, t1.y);
            un[p] = ui[p] ^ 0x80008000u;
        }
        fA[(lane*2 + mt)*3 + 0] = make_uint4(ur[0],ur[1],ur[2],ur[3]);
        fA[(lane*2 + mt)*3 + 1] = make_uint4(ui[0],ui[1],ui[2],ui[3]);
        fA[(lane*2 + mt)*3 + 2] = make_uint4(un[0],un[1],un[2],un[3]);
    }
    for (int k2 = 0; k2 < 16; ++k2) {
        uint ar[4]={0,0,0,0}, ai[4]={0,0,0,0}, an[4]={0,0,0,0};
        if (lane < 32) {
            const int kk = k2 + 32*l15;
            for (int p = 0; p < 4; ++p) {
                float2 t0 = twf((kb + 2*p)*kk);
                float2 t1 = twf((kb + 2*p+1)*kk);
                ar[p] = packh(t0.x, t1.x);
                ai[p] = packh(t0.y, t1.y);
                an[p] = ai[p] ^ 0x80008000u;
            }
        }
        fB[(lane*16 + k2)*3 + 0] = make_uint4(ar[0],ar[1],ar[2],ar[3]);
        fB[(lane*16 + k2)*3 + 1] = make_uint4(ai[0],ai[1],ai[2],ai[3]);
        fB[(lane*16 + k2)*3 + 2] = make_uint4(an[0],an[1],an[2],an[3]);
    }
    {
        uint gr[4]={0,0,0,0}, gi[4]={0,0,0,0}, gn[4]={0,0,0,0};
        if (lane < 32) {
            for (int p = 0; p < 4; ++p) {
                float2 t0 = twf(32*(kb + 2*p)*l15);
                float2 t1 = twf(32*(kb + 2*p+1)*l15);
                gr[p] = packh(t0.x, t1.x);
                gi[p] = packh(-t0.y, -t1.y);
                gn[p] = gi[p] ^ 0x80008000u;
            }
        }
        fG[lane*3 + 0] = make_uint4(gr[0],gr[1],gr[2],gr[3]);
        fG[lane*3 + 1] = make_uint4(gi[0],gi[1],gi[2],gi[3]);
        fG[lane*3 + 2] = make_uint4(gn[0],gn[1],gn[2],gn[3]);
    }
    for (int n1 = 0; n1 < 16; ++n1)
        for (int mt = 0; mt < 2; ++mt) {
            const int hh = n1 + 16*(mt*16 + l15);
            uint cr[4], ci[4], cn[4];
            for (int p = 0; p < 4; ++p) {
                float2 t0 = twf(hh*(kb + 2*p));
                float2 t1 = twf(hh*(kb + 2*p+1));
                cr[p] = packh(t0.x, t1.x);
                ci[p] = packh(-t0.y, -t1.y);
                cn[p] = ci[p] ^ 0x80008000u;
            }
            fC[((lane*16 + n1)*2 + mt)*3 + 0] = make_uint4(cr[0],cr[1],cr[2],cr[3]);
            fC[((lane*16 + n1)*2 + mt)*3 + 1] = make_uint4(ci[0],ci[1],ci[2],ci[3]);
            fC[((lane*16 + n1)*2 + mt)*3 + 2] = make_uint4(cn[0],cn[1],cn[2],cn[3]);
        }
}

__global__ void k_wprep(const float* __restrict__ w, ushort* __restrict__ wtp){
    int i = blockIdx.x*256 + threadIdx.x;
    if (i < 9216) {
        int j = i & 7, l = (i>>3) & 63, m = (i>>9) & 1, tap = i >> 10;
        int co = m*16 + (l & 15), ci = ((l>>4)&3)*8 + j;
        wtp[i] = f2bf(w[(co*32 + ci)*9 + tap]);
    }
}

// ---------------- NCHW fp32 -> NHWC bf16 transpose ----------------
__global__ __launch_bounds__(256) void k_transpose(const float* __restrict__ x, ushort* __restrict__ xt){
    __shared__ ushort tl[64][36];
    const int tid = threadIdx.x;
    const int w0 = blockIdx.x*64, h = blockIdx.y, b = blockIdx.z;
    #pragma unroll
    for (int it = 0; it < 8; ++it) {
        int i = it*256 + tid, c = i >> 6, ww = i & 63;
        tl[ww][c] = f2bf(x[(((size_t)b*32 + c)*512 + h)*512 + w0 + ww]);
    }
    __syncthreads();
    const int ww = tid >> 2, c0 = (tid & 3) * 8;
    uint4 v;
    v.x = *(const uint*)&tl[ww][c0+0];
    v.y = *(const uint*)&tl[ww][c0+2];
    v.z = *(const uint*)&tl[ww][c0+4];
    v.w = *(const uint*)&tl[ww][c0+6];
    *(uint4*)(xt + ((((size_t)b*512 + h)*512 + w0 + ww)*32 + c0)) = v;
}

// ---------------- conv 3x3 via bf16 MFMA, bf16 out, fused bias + BN1 stats ----------------
__global__ __launch_bounds__(256) void k_conv_mfma(
    const ushort* __restrict__ xt, const ushort* __restrict__ wtp,
    const float* __restrict__ bias, ushort* __restrict__ out, float* __restrict__ stats)
{
    __shared__ float sred[64];
    const int tid = threadIdx.x;
    const int wid = tid >> 6, lane = tid & 63;
    const int h = blockIdx.y*4 + wid;
    const int w0 = blockIdx.x*64;
    const int b = blockIdx.z;

    short8 wa[9][2];
    #pragma unroll
    for (int tap = 0; tap < 9; ++tap)
        #pragma unroll
        for (int m = 0; m < 2; ++m)
            wa[tap][m] = *reinterpret_cast<const short8*>(wtp + ((tap*2 + m)*64 + lane)*8);

    f32x4 acc[2][4];
    #pragma unroll
    for (int m = 0; m < 2; ++m)
        #pragma unroll
        for (int n = 0; n < 4; ++n)
            acc[m][n] = (f32x4){0.f, 0.f, 0.f, 0.f};

    const int c0 = ((lane >> 4) & 3) * 8;
    const int pw = w0 + (lane & 15);
    const size_t ibase = (size_t)b * 512 * 512;

    #pragma unroll
    for (int dy = -1; dy <= 1; ++dy) {
        const int hh = h + dy;
        const bool hok = (unsigned)hh < 512u;
        #pragma unroll
        for (int dx = -1; dx <= 1; ++dx) {
            const int tap = (dy+1)*3 + (dx+1);
            short8 bfr[4];
            #pragma unroll
            for (int n = 0; n < 4; ++n) {
                const int ww = pw + n*16 + dx;
                short8 v = {0,0,0,0,0,0,0,0};
                if (hok && (unsigned)ww < 512u)
                    v = *reinterpret_cast<const short8*>(xt + ((ibase + (size_t)hh*512 + ww)*32 + c0));
                bfr[n] = v;
            }
            #pragma unroll
            for (int m = 0; m < 2; ++m)
                #pragma unroll
                for (int n = 0; n < 4; ++n)
                    acc[m][n] = __builtin_amdgcn_mfma_f32_16x16x32_bf16(wa[tap][m], bfr[n], acc[m][n], 0, 0, 0);
        }
    }

    if (tid < 64) sred[tid] = 0.f;
    __syncthreads();

    float bv[2][4];
    #pragma unroll
    for (int m = 0; m < 2; ++m)
        #pragma unroll
        for (int r = 0; r < 4; ++r)
            bv[m][r] = bias[m*16 + ((lane>>4)&3)*4 + r];

    float s8[8], q8[8];
    #pragma unroll
    for (int i = 0; i < 8; ++i) { s8[i] = 0.f; q8[i] = 0.f; }

    #pragma unroll
    for (int m = 0; m < 2; ++m) {
        #pragma unroll
        for (int n = 0; n < 4; ++n) {
            #pragma unroll
            for (int r = 0; r < 4; ++r) {
                const int co = m*16 + ((lane>>4)&3)*4 + r;
                const int ww = w0 + n*16 + (lane & 15);
                float val = acc[m][n][r] + bv[m][r];
                out[(((size_t)b*32 + co)*512 + h)*512 + ww] = f2bf(val);
                s8[m*4+r] += val;
                q8[m*4+r] += val*val;
            }
        }
    }
    #pragma unroll
    for (int i = 0; i < 8; ++i) {
        #pragma unroll
        for (int off = 1; off < 16; off <<= 1) {
            s8[i] += __shfl_xor(s8[i], off, 64);
            q8[i] += __shfl_xor(q8[i], off, 64);
        }
    }
    if ((lane & 15) == 0) {
        #pragma unroll
        for (int m = 0; m < 2; ++m)
            #pragma unroll
            for (int r = 0; r < 4; ++r) {
                const int co = m*16 + ((lane>>4)&3)*4 + r;
                atomicAdd(&sred[co], s8[m*4+r]);
                atomicAdd(&sred[32+co], q8[m*4+r]);
            }
    }
    __syncthreads();
    if (tid < 64) {
        int bin = (blockIdx.y*8 + blockIdx.x + blockIdx.z) & 63;
        atomicAdd(&stats[bin*64 + tid], sred[tid]);
    }
}

__global__ void k_finalize(const float* __restrict__ stats, int nbins, const float* __restrict__ g,
                           const float* __restrict__ bta, float* __restrict__ bnp)
{
    int c = threadIdx.x;
    if (c < 32) {
        float s = 0.f, q = 0.f;
        for (int i = 0; i < nbins; ++i) { s += stats[i*64 + c]; q += stats[i*64 + 32 + c]; }
        const float inv_n = 1.f/1048576.f;
        float mean = s * inv_n;
        float var  = q * inv_n - mean*mean;
        float sc = g[c] * rsqrtf(var + 1e-5f);
        bnp[c] = sc;
        bnp[32+c] = bta[c] - mean*sc;
    }
}

__global__ void k_finalize2(const float* __restrict__ ystats, const float* __restrict__ sstats,
                            const float* __restrict__ g, const float* __restrict__ bta,
                            float* __restrict__ bnp2)
{
    int c = threadIdx.x;
    if (c < 32) {
        float Sy = 0.f, Sy2 = 0.f, Sgg = 0.f, Sgu = 0.f, Sg0 = 0.f;
        for (int i = 0; i < 64; ++i){ Sy  += ystats[i*64 + c]; Sy2 += ystats[i*64 + 32 + c]; }
        for (int i = 0; i < 32; ++i){ Sgg += sstats[i*96 + c]; Sgu += sstats[i*96 + 32 + c]; Sg0 += sstats[i*96 + 64 + c]; }
        const float inv_n = 1.f/1048576.f;
        float Sfo  = Sg0 + Sy;
        float Sfo2 = Sgg*(1.f/512.f) + Sgu*(2.f/512.f) + Sy2;
        float mean = Sfo*inv_n;
        float var  = Sfo2*inv_n - mean*mean;
        float sc = g[c]*rsqrtf(var + 1e-5f);
        bnp2[c] = sc;
        bnp2[32+c] = bta[c] - mean*sc;
    }
}

// ---------------- row rfft: wave-local FFT (2 real rows per wave), bf16 in/out ----------------
__global__ __launch_bounds__(512) void k_rowfft_fwd(
    const ushort* __restrict__ cvo, const float* __restrict__ bnp,
    const float2* __restrict__ twg, uint* __restrict__ spec, float* __restrict__ ystats)
{
    __shared__ float2 tw[512];
    __shared__ uint d[8*ROWH];
    const int tid = threadIdx.x;
    const int h0 = blockIdx.x * 16;
    const int bc = blockIdx.y;
    const int c = bc & 31;
    ld_tw<512>(tw, twg, tid);
    __syncthreads();
    const float s1 = bnp[c], t1 = bnp[32+c];
    const int row = tid >> 6, l = tid & 63;
    const int o0 = ((l&7)<<3) | (l>>3);
    uint* drow = d + row*ROWH;
    const ushort* rp0 = cvo + ((size_t)bc*512 + h0 + 2*row)*512 + o0;
    const ushort* rp1 = rp0 + 512;
    float ls = 0.f, lsq = 0.f;
    float2 v[8];
    #pragma unroll
    for (int q = 0; q < 8; ++q) {
        float y0 = fmaxf(fmaf(bf2f(rp0[64*q]), s1, t1), 0.f);
        float y1 = fmaxf(fmaf(bf2f(rp1[64*q]), s1, t1), 0.f);
        ls += y0 + y1; lsq += y0*y0 + y1*y1;
        v[q] = make_float2(y0, y1);
    }
    dft8<false>(v);
    oct_write(drow, l, v);
    fft_wave12<false>(drow, tw, l);
    __syncthreads();
    for (int i = tid; i < 8*WF; i += 512) {
        int p = i & 7, w = i >> 3;
        float2 Z  = unph(d[p*ROWH + LPH(w)]);
        float2 Zm = unph(d[p*ROWH + LPH((512 - w) & 511)]);
        float x1r = 0.5f*(Z.x + Zm.x), x1i = 0.5f*(Z.y - Zm.y);
        float x2r = 0.5f*(Z.y + Zm.y), x2i = 0.5f*(Zm.x - Z.x);
        uint2 pk;
        pk.x = packbf(x1r, x1i);
        pk.y = packbf(x2r, x2i);
        *(uint2*)(spec + ((size_t)bc*WF + w)*512 + h0 + 2*p) = pk;
    }
    #pragma unroll
    for (int off = 32; off; off >>= 1){ ls += __shfl_down(ls, off, 64); lsq += __shfl_down(lsq, off, 64); }
    if (l == 0) {
        int bin = ((blockIdx.x << 3) + row) & 63;
        atomicAdd(&ystats[bin*64 + c], ls);
        atomicAdd(&ystats[bin*64 + 32 + c], lsq);
    }
}

// ---------------- col transform via f16 MFMA (precomputed fragments; R11 indexing) ----------------
__global__ __launch_bounds__(512) void k_colfft(uint* __restrict__ spec,
    const float* __restrict__ w1, const float* __restrict__ b1,
    const float* __restrict__ w2, const float* __restrict__ b2,
    const uint4* __restrict__ fA, const uint4* __restrict__ fB,
    const uint4* __restrict__ fG, const uint4* __restrict__ fC,
    float* __restrict__ sstats)
{
    __shared__ uint sl[32*513];
    __shared__ float wl[640];
    const int tid = threadIdx.x;
    const int lane = tid & 63, wv = tid >> 6;
    const int w = blockIdx.x, b = blockIdx.y;
    const int l15 = lane & 15, lq = lane >> 4;
    const int kb = lq * 8;

    if (tid < 128) {
        int g = tid >> 4, j = tid & 15;
        wl[g*80 + j]      = w1[g*16 + j];
        wl[g*80 + 16 + j] = w1[128 + g*16 + j];
        wl[g*80 + 32 + j] = w2[g*16 + j];
        wl[g*80 + 48 + j] = w2[128 + g*16 + j];
    } else if (tid < 160) {
        int t2 = tid - 128, g = t2 >> 2, o = t2 & 3;
        wl[g*80 + 64 + o] = b1[g*4 + o];
        wl[g*80 + 68 + o] = b1[32 + g*4 + o];
        wl[g*80 + 72 + o] = b2[g*4 + o];
        wl[g*80 + 76 + o] = b2[32 + g*4 + o];
    }
    const size_t gbase = ((size_t)b*32*WF + w) * 512;
    #pragma unroll 4
    for (int c = 0; c < 32; ++c) {
        float2 u = unpackbf(spec[gbase + (size_t)c*(WF*512) + tid]);
        sl[c*513 + tid] = packh(u.x*(1.f/512.f), u.y*(1.f/512.f));
    }
    __syncthreads();

    // ===== forward stage A (K=32)
    {
        h8 Fr[2], Fi[2], nFi[2];
        #pragma unroll
        for (int mt = 0; mt < 2; ++mt) {
            UH8 a; a.u = fA[(lane*2 + mt)*3 + 0]; Fr[mt]=a.h;
            UH8 bb; bb.u = fA[(lane*2 + mt)*3 + 1]; Fi[mt]=bb.h;
            UH8 cc; cc.u = fA[(lane*2 + mt)*3 + 2]; nFi[mt]=cc.h;
        }
        #pragma unroll
        for (int s = 0; s < 2; ++s) {
            const int n1 = wv*2 + s;
            h8 Br[2], Bi[2];
            #pragma unroll
            for (int nt = 0; nt < 2; ++nt) {
                const int base = (nt*16 + l15)*513 + n1;
                uint dd[8];
                #pragma unroll
                for (int j = 0; j < 8; ++j) dd[j] = sl[base + 16*(kb + j)];
                uint br[4], bi[4];
                #pragma unroll
                for (int p = 0; p < 4; ++p) {
                    br[p] = (dd[2*p] & 0xffffu) | (dd[2*p+1] << 16);
                    bi[p] = (dd[2*p] >> 16) | (dd[2*p+1] & 0xffff0000u);
                }
                UH8 t1_; t1_.u = make_uint4(br[0],br[1],br[2],br[3]); Br[nt]=t1_.h;
                UH8 t2_; t2_.u = make_uint4(bi[0],bi[1],bi[2],bi[3]); Bi[nt]=t2_.h;
            }
            #pragma unroll
            for (int mt = 0; mt < 2; ++mt)
            #pragma unroll
            for (int nt = 0; nt < 2; ++nt) {
                f32x4 yr = {0.f,0.f,0.f,0.f}, yi = {0.f,0.f,0.f,0.f};
                yr = __builtin_amdgcn_mfma_f32_16x16x32_f16(Fr[mt], Br[nt], yr, 0,0,0);
                yr = __builtin_amdgcn_mfma_f32_16x16x32_f16(nFi[mt], Bi[nt], yr, 0,0,0);
                yi = __builtin_amdgcn_mfma_f32_16x16x32_f16(Fr[mt], Bi[nt], yi, 0,0,0);
                yi = __builtin_amdgcn_mfma_f32_16x16x32_f16(Fi[mt], Br[nt], yi, 0,0,0);
                const int cw = (nt*16 + l15)*513 + n1;
                #pragma unroll
                for (int r = 0; r < 4; ++r)
                    sl[cw + 16*(mt*16 + lq*4 + r)] = packh(yr[r], yi[r]);
            }
        }
    }
    __syncthreads();

    // ===== forward stage B (K=16)
    #pragma unroll
    for (int s = 0; s < 4; ++s) {
        const int k2 = wv*4 + s;
        h8 Ar, Ai, nAi;
        {
            UH8 a; a.u = fB[(lane*16 + k2)*3 + 0]; Ar=a.h;
            UH8 bb; bb.u = fB[(lane*16 + k2)*3 + 1]; Ai=bb.h;
            UH8 cc; cc.u = fB[(lane*16 + k2)*3 + 2]; nAi=cc.h;
        }
        #pragma unroll
        for (int ct = 0; ct < 2; ++ct) {
            const int cb2 = (ct*16 + l15)*513 + 16*k2;
            h8 Br, Bi;
            {
                uint dd[8] = {0,0,0,0,0,0,0,0};
                if (lane < 32) {
                    #pragma unroll
                    for (int j = 0; j < 8; ++j) dd[j] = sl[cb2 + kb + j];
                }
                uint br[4], bi[4];
                #pragma unroll
                for (int p = 0; p < 4; ++p) {
                    br[p] = (dd[2*p] & 0xffffu) | (dd[2*p+1] << 16);
                    bi[p] = (dd[2*p] >> 16) | (dd[2*p+1] & 0xffff0000u);
                }
                UH8 t1_; t1_.u = make_uint4(br[0],br[1],br[2],br[3]); Br=t1_.h;
                UH8 t2_; t2_.u = make_uint4(bi[0],bi[1],bi[2],bi[3]); Bi=t2_.h;
            }
            f32x4 xr = {0.f,0.f,0.f,0.f}, xi = {0.f,0.f,0.f,0.f};
            xr = __builtin_amdgcn_mfma_f32_16x16x32_f16(Ar, Br, xr, 0,0,0);
            xr = __builtin_amdgcn_mfma_f32_16x16x32_f16(nAi, Bi, xr, 0,0,0);
            xi = __builtin_amdgcn_mfma_f32_16x16x32_f16(Ar, Bi, xi, 0,0,0);
            xi = __builtin_amdgcn_mfma_f32_16x16x32_f16(Ai, Br, xi, 0,0,0);
            #pragma unroll
            for (int r = 0; r < 4; ++r)
                sl[cb2 + lq*4 + r] = packh(xr[r], xi[r]);
        }
    }
    __syncthreads();

    // ===== MLP + softshrink + gate (pointwise)
    #pragma unroll
    for (int g = 0; g < 8; ++g) {
        const float* wk = wl + g*80;
        float xr[4], xi[4];
        #pragma unroll
        for (int i = 0; i < 4; ++i) {
            float2 v = unph(sl[(4*g+i)*513 + tid]);
            xr[i] = v.x; xi[i] = v.y;
        }
        float o1r[4], o1i[4];
        #pragma unroll
        for (int o = 0; o < 4; ++o) {
            float sr = wk[64+o], si = wk[68+o];
            #pragma unroll
            for (int i = 0; i < 4; ++i) {
                float wr = wk[i*4+o], wi = wk[16 + i*4+o];
                sr += xr[i]*wr - xi[i]*wi;
                si += xi[i]*wr + xr[i]*wi;
            }
            o1r[o] = fmaxf(sr, 0.f);
            o1i[o] = fmaxf(si, 0.f);
        }
        #pragma unroll
        for (int o = 0; o < 4; ++o) {
            float sr = wk[72+o], si = wk[76+o];
            #pragma unroll
            for (int i = 0; i < 4; ++i) {
                float wr = wk[32 + i*4+o], wi = wk[48 + i*4+o];
                sr += o1r[i]*wr - o1i[i]*wi;
                si += o1i[i]*wr + o1r[i]*wi;
            }
            sr = (sr > LAM) ? sr - LAM : ((sr < -LAM) ? sr + LAM : 0.f);
            si = (si > LAM) ? si - LAM : ((si < -LAM) ? si + LAM : 0.f);
            sl[(4*g+o)*513 + tid] = packh(sr*xr[o] - si*xi[o], sr*xi[o] + si*xr[o]);
        }
    }
    __syncthreads();

    // ===== inverse stage 1 (K=16)
    {
        h8 Gr, Gi, nGi;
        {
            UH8 a; a.u = fG[lane*3 + 0]; Gr=a.h;
            UH8 bb; bb.u = fG[lane*3 + 1]; Gi=bb.h;
            UH8 cc; cc.u = fG[lane*3 + 2]; nGi=cc.h;
        }
        #pragma unroll
        for (int s = 0; s < 4; ++s) {
            const int k2 = wv*4 + s;
            #pragma unroll
            for (int ct = 0; ct < 2; ++ct) {
                const int cb2 = (ct*16 + l15)*513 + 16*k2;
                h8 Br, Bi;
                {
                    uint dd[8] = {0,0,0,0,0,0,0,0};
                    if (lane < 32) {
                        #pragma unroll
                        for (int j = 0; j < 8; ++j) dd[j] = sl[cb2 + kb + j];
                    }
                    uint br[4], bi[4];
                    #pragma unroll
                    for (int p = 0; p < 4; ++p) {
                        br[p] = (dd[2*p] & 0xffffu) | (dd[2*p+1] << 16);
                        bi[p] = (dd[2*p] >> 16) | (dd[2*p+1] & 0xffff0000u);
                    }
                    UH8 t1_; t1_.u = make_uint4(br[0],br[1],br[2],br[3]); Br=t1_.h;
                    UH8 t2_; t2_.u = make_uint4(bi[0],bi[1],bi[2],bi[3]); Bi=t2_.h;
                }
                f32x4 yr = {0.f,0.f,0.f,0.f}, yi = {0.f,0.f,0.f,0.f};
                yr = __builtin_amdgcn_mfma_f32_16x16x32_f16(Gr, Br, yr, 0,0,0);
                yr = __builtin_amdgcn_mfma_f32_16x16x32_f16(nGi, Bi, yr, 0,0,0);
                yi = __builtin_amdgcn_mfma_f32_16x16x32_f16(Gr, Bi, yi, 0,0,0);
                yi = __builtin_amdgcn_mfma_f32_16x16x32_f16(Gi, Br, yi, 0,0,0);
                #pragma unroll
                for (int r = 0; r < 4; ++r)
                    sl[cb2 + lq*4 + r] = packh(yr[r], yi[r]);
            }
        }
    }
    __syncthreads();

    // ===== inverse stage 2 (K=32)
    #pragma unroll
    for (int s = 0; s < 2; ++s) {
        const int n1 = wv*2 + s;
        h8 Cr[2], Ci[2], nCi[2];
        #pragma unroll
        for (int mt = 0; mt < 2; ++mt) {
            UH8 a; a.u = fC[((lane*16 + n1)*2 + mt)*3 + 0]; Cr[mt]=a.h;
            UH8 bb; bb.u = fC[((lane*16 + n1)*2 + mt)*3 + 1]; Ci[mt]=bb.h;
            UH8 cc; cc.u = fC[((lane*16 + n1)*2 + mt)*3 + 2]; nCi[mt]=cc.h;
        }
        h8 Br[2], Bi[2];
        #pragma unroll
        for (int nt = 0; nt < 2; ++nt) {
            const int base = (nt*16 + l15)*513 + n1;
            uint dd[8];
            #pragma unroll
            for (int j = 0; j < 8; ++j) dd[j] = sl[base + 16*(kb + j)];
            uint br[4], bi[4];
            #pragma unroll
            for (int p = 0; p < 4; ++p) {
                br[p] = (dd[2*p] & 0xffffu) | (dd[2*p+1] << 16);
                bi[p] = (dd[2*p] >> 16) | (dd[2*p+1] & 0xffff0000u);
            }
            UH8 t1_; t1_.u = make_uint4(br[0],br[1],br[2],br[3]); Br[nt]=t1_.h;
            UH8 t2_; t2_.u = make_uint4(bi[0],bi[1],bi[2],bi[3]); Bi[nt]=t2_.h;
        }
        #pragma unroll
        for (int mt = 0; mt < 2; ++mt)
        #pragma unroll
        for (int nt = 0; nt < 2; ++nt) {
            f32x4 xr = {0.f,0.f,0.f,0.f}, xi = {0.f,0.f,0.f,0.f};
            xr = __builtin_amdgcn_mfma_f32_16x16x32_f16(Cr[mt], Br[nt], xr, 0,0,0);
            xr = __builtin_amdgcn_mfma_f32_16x16x32_f16(nCi[mt], Bi[nt], xr, 0,0,0);
            xi = __builtin_amdgcn_mfma_f32_16x16x32_f16(Cr[mt], Bi[nt], xi, 0,0,0);
            xi = __builtin_amdgcn_mfma_f32_16x16x32_f16(Ci[mt], Br[nt], xi, 0,0,0);
            const int cw = (nt*16 + l15)*513 + n1;
            #pragma unroll
            for (int r = 0; r < 4; ++r)
                sl[cw + 16*(mt*16 + lq*4 + r)] = packh(xr[r], xi[r]);
        }
    }
    __syncthreads();

    // ===== epilogue: bf16 write-back + Parseval sums
    const bool edge = (w == 0) || (w == 256);
    #pragma unroll
    for (int i = 0; i < 4; ++i) {
        const int c = wv*4 + i;
        const size_t cb = gbase + (size_t)c*(WF*512);
        float fgg = 0.f, fgu = 0.f, fg0 = 0.f;
        #pragma unroll
        for (int it = 0; it < 4; ++it) {
            const int pos = it*128 + 2*lane;
            uint2 dv;
            dv.x = sl[c*513 + pos];
            dv.y = sl[c*513 + pos + 1];
            float2 z0 = unph(dv.x), z1 = unph(dv.y);
            uint2 up = *(const uint2*)(spec + cb + pos);
            float2 u0 = unpackbf(up.x), u1 = unpackbf(up.y);
            uint2 gp;
            gp.x = packbf(z0.x, z0.y);
            gp.y = packbf(z1.x, z1.y);
            *(uint2*)(spec + cb + pos) = gp;
            float2 g0 = unpackbf(gp.x), g1 = unpackbf(gp.y);
            if (edge) {
                fgg += g0.x*g0.x + g1.x*g1.x;
                fgu += g0.x*u0.x + g1.x*u1.x;
                if (w == 0) fg0 += g0.x + g1.x;
            } else {
                fgg += 2.f*(g0.x*g0.x + g0.y*g0.y + g1.x*g1.x + g1.y*g1.y);
                fgu += 2.f*(g0.x*u0.x + g0.y*u0.y + g1.x*u1.x + g1.y*u1.y);
            }
        }
        #pragma unroll
        for (int off = 32; off; off >>= 1){
            fgg += __shfl_down(fgg, off, 64);
            fgu += __shfl_down(fgu, off, 64);
            fg0 += __shfl_down(fg0, off, 64);
        }
        if (lane == 0) {
            const int kk = c >> 2, ch = c & 3;
            const int bin = (w + b*8 + kk) & 31;
            atomicAdd(&sstats[bin*96 + kk*4 + ch], fgg);
            atomicAdd(&sstats[bin*96 + 32 + kk*4 + ch], fgu);
            if (w == 0) atomicAdd(&sstats[bin*96 + 64 + kk*4 + ch], fg0);
        }
    }
}

// ---------------- row irfft: wave-local inverse FFT + BN2 + final ReLU ----------------
__global__ __launch_bounds__(512) void k_rowfft_inv(
    const uint* __restrict__ spec, const ushort* __restrict__ cvo,
    const float* __restrict__ bnp, const float* __restrict__ bnp2,
    const float2* __restrict__ twg, float* __restrict__ out)
{
    __shared__ float2 tw[512];
    __shared__ uint d[8*ROWH];
    const int tid = threadIdx.x;
    const int h0 = blockIdx.x * 16;
    const int bc = blockIdx.y;
    const int c = bc & 31;
    ld_tw<512>(tw, twg, tid);
    for (int i = tid; i < 8*WF; i += 512) {
        int p = i & 7, w = i >> 3;
        uint2 pk = *(const uint2*)(spec + ((size_t)bc*WF + w)*512 + h0 + 2*p);
        float2 X1 = unpackbf(pk.x), X2 = unpackbf(pk.y);
        if (w == 0 || w == 256) { X1.y = 0.f; X2.y = 0.f; }
        const float s = 1.f/512.f;
        d[p*ROWH + LPH(w)] = packh((X1.x - X2.y)*s, (X1.y + X2.x)*s);
        if ((unsigned)(w - 1) < 255u)
            d[p*ROWH + LPH(512 - w)] = packh((X1.x + X2.y)*s, (X2.x - X1.y)*s);
    }
    __syncthreads();
    const int row = tid >> 6, l = tid & 63;
    const int o0 = ((l&7)<<3) | (l>>3);
    uint* drow = d + row*ROWH;
    {
        float2 v[8];
        oct_gather(drow, o0, v);
        dft8<true>(v);
        WSYNC();
        oct_write(drow, l, v);
    }
    fft_wave12<true>(drow, tw, l);
    const float s1 = bnp[c],  t1 = bnp[32+c];
    const float s2 = bnp2[c], t2 = bnp2[32+c];
    const size_t gbase = ((size_t)bc*512 + h0 + 2*row)*512;
    #pragma unroll
    for (int q = 0; q < 8; ++q) {
        const int col = q*64 + l;
        float2 v = unph(drow[LPH(col)]);
        float y0 = fmaxf(fmaf(bf2f(cvo[gbase + col]), s1, t1), 0.f);
        float fo0 = v.x + y0;
        out[gbase + col] = fmaxf(y0 + fmaf(fo0, s2, t2), 0.f);
        float y1 = fmaxf(fmaf(bf2f(cvo[gbase + 512 + col]), s1, t1), 0.f);
        float fo1 = v.y + y1;
        out[gbase + 512 + col] = fmaxf(y1 + fmaf(fo1, s2, t2), 0.f);
    }
}

extern "C" void kernel_launch(void* const* d_in, const int* in_sizes, int n_in,
                              void* d_out, int out_size, void* d_ws, size_t ws_size,
                              hipStream_t stream)
{
    const float* x      = (const float*)d_in[0];
    const float* conv_w = (const float*)d_in[1];
    const float* conv_b = (const float*)d_in[2];
    const float* bn1g   = (const float*)d_in[3];
    const float* bn1b   = (const float*)d_in[4];
    const float* w1     = (const float*)d_in[5];
    const float* b1     = (const float*)d_in[6];
    const float* w2     = (const float*)d_in[7];
    const float* b2     = (const float*)d_in[8];
    const float* bn2g   = (const float*)d_in[9];
    const float* bn2b   = (const float*)d_in[10];
    float* out = (float*)d_out;

    char* ws = (char*)d_ws;
    uint*   spec  = (uint*)ws;                              // 67,371,008 B (bf16 pairs)
    ushort* xt    = (ushort*)ws;                            // aliases spec (dead before spec written)
    ushort* cvo   = (ushort*)(ws + 67371008);               // 67,108,864 B (bf16)
    ushort* wtp   = (ushort*)(ws + 67371008 + 67108864);    // 18,432 B
    float*  stats = (float*)(ws + 67371008 + 67108864 + 18432);
    float* stats1 = stats;             // 4096 f (bn1 bins)
    float* ystats = stats + 4096;      // 4096 f
    float* sstats = stats + 8192;      // 3072 f
    float* bnp1   = stats + 11264;     // 64 f
    float* bnp2   = stats + 11328;     // 64 f
    float2* twg   = (float2*)(stats + 11392); // 512 float2 (ends at stats+12416)
    uint4* fA = (uint4*)(stats + 12416);      // 384 uint4
    uint4* fB = fA + 384;                     // 3072 uint4
    uint4* fG = fB + 3072;                    // 192 uint4
    uint4* fC = fG + 192;                     // 6144 uint4

    (void)hipMemsetAsync(stats, 0, 11264*sizeof(float), stream);
    k_twiddle<<<2, 256, 0, stream>>>(twg);
    k_mfrag<<<1, 64, 0, stream>>>(fA, fB, fG, fC);
    k_wprep<<<36, 256, 0, stream>>>(conv_w, wtp);
    k_transpose<<<dim3(8,512,4), 256, 0, stream>>>(x, xt);
    k_conv_mfma<<<dim3(8,128,4), 256, 0, stream>>>(xt, wtp, conv_b, cvo, stats1);
    k_finalize<<<1, 64, 0, stream>>>(stats1, 64, bn1g, bn1b, bnp1);
    k_rowfft_fwd<<<dim3(32,128), 512, 0, stream>>>(cvo, bnp1, twg, spec, ystats);
    k_colfft<<<dim3(257,4), 512, 0, stream>>>(spec, w1, b1, w2, b2, fA, fB, fG, fC, sstats);
    k_finalize2<<<1, 64, 0, stream>>>(ystats, sstats, bn2g, bn2b, bnp2);
    k_rowfft_inv<<<dim3(32,128), 512, 0, stream>>>(spec, cvo, bnp1, bnp2, twg, out);
}

// Round 14
// 330.347 us; speedup vs baseline: 1.1778x; 1.1778x over previous
//
#include <hip/hip_runtime.h>

#define WF 257
#define LAM 0.01f
#define ROWH 540
#define LPH(i) ((i) + (((i)>>6)<<2))

#define WSYNC() do { asm volatile("" ::: "memory"); __builtin_amdgcn_wave_barrier(); asm volatile("" ::: "memory"); } while(0)

typedef __attribute__((ext_vector_type(8))) short short8;
typedef __attribute__((ext_vector_type(4))) float f32x4;
typedef __attribute__((ext_vector_type(2))) __fp16 h2v;
typedef __attribute__((ext_vector_type(8))) __fp16 h8;

union UH8 { uint4 u; h8 h; };

__device__ __forceinline__ ushort f2bf(float f){
    unsigned u = __float_as_uint(f);
    unsigned r = (u + 0x7fffu + ((u >> 16) & 1u)) >> 16;
    return (ushort)r;
}
__device__ __forceinline__ float bf2f(ushort u){ return __uint_as_float((uint)u << 16); }
__device__ __forceinline__ uint packbf(float a, float b){
    return (uint)f2bf(a) | ((uint)f2bf(b) << 16);
}
__device__ __forceinline__ float2 unpackbf(uint u){
    return make_float2(__uint_as_float(u << 16), __uint_as_float(u & 0xffff0000u));
}
// fp16x2 pack, round-to-nearest-even (v_cvt_f16_f32 + v_pack)
__device__ __forceinline__ uint packh(float a, float b){
    h2v h;
    h[0] = (__fp16)a;
    h[1] = (__fp16)b;
    return *(uint*)&h;
}
__device__ __forceinline__ uint packh2(float2 v){ return packh(v.x, v.y); }
__device__ __forceinline__ float2 unph(uint u){
    h2v h = *(h2v*)&u;
    return make_float2((float)h[0], (float)h[1]);
}

__device__ __forceinline__ float2 cmul(float2 a, float2 b){
    return make_float2(a.x*b.x - a.y*b.y, a.x*b.y + a.y*b.x);
}
__device__ __forceinline__ float2 cadd(float2 a, float2 b){ return make_float2(a.x+b.x, a.y+b.y); }
__device__ __forceinline__ float2 csub(float2 a, float2 b){ return make_float2(a.x-b.x, a.y-b.y); }

template<int NTHREADS>
__device__ __forceinline__ void ld_tw(float2* tw, const float2* __restrict__ twg, int tid){
    for (int t = tid; t < 256; t += NTHREADS)
        ((float4*)tw)[t] = ((const float4*)twg)[t];
}

template<bool INV>
__device__ __forceinline__ float2 twz(const float2* tw, int idx){
    float2 w = tw[idx];
    if (INV) w.y = -w.y;
    return w;
}

template<bool INV>
__device__ __forceinline__ void dft8(float2 v[8]) {
    const float R = 0.70710678118654752f;
    float2 y0=v[0], y1=v[4], y2=v[2], y3=v[6], y4=v[1], y5=v[5], y6=v[3], y7=v[7];
    float2 t;
    t=y1; y1=csub(y0,t); y0=cadd(y0,t);
    t=y3; y3=csub(y2,t); y2=cadd(y2,t);
    t=y5; y5=csub(y4,t); y4=cadd(y4,t);
    t=y7; y7=csub(y6,t); y6=cadd(y6,t);
    t=y2; y2=csub(y0,t); y0=cadd(y0,t);
    t = INV ? make_float2(-y3.y, y3.x) : make_float2(y3.y, -y3.x);
    y3=csub(y1,t); y1=cadd(y1,t);
    t=y6; y6=csub(y4,t); y4=cadd(y4,t);
    t = INV ? make_float2(-y7.y, y7.x) : make_float2(y7.y, -y7.x);
    y7=csub(y5,t); y5=cadd(y5,t);
    t=y4; y4=csub(y0,t); y0=cadd(y0,t);
    { float2 w8 = INV ? make_float2(R, R) : make_float2(R,-R);
      t=cmul(y5,w8); y5=csub(y1,t); y1=cadd(y1,t); }
    t = INV ? make_float2(-y6.y, y6.x) : make_float2(y6.y, -y6.x);
    y6=csub(y2,t); y2=cadd(y2,t);
    { float2 w8 = INV ? make_float2(-R, R) : make_float2(-R,-R);
      t=cmul(y7,w8); y7=csub(y3,t); y3=cadd(y3,t); }
    v[0]=y0; v[1]=y1; v[2]=y2; v[3]=y3; v[4]=y4; v[5]=y5; v[6]=y6; v[7]=y7;
}

__device__ __forceinline__ void oct_write(uint* drow, int l, const float2 v[8]){
    uint* p = drow + LPH(8*l);
    *(uint4*)p       = make_uint4(packh2(v[0]), packh2(v[1]), packh2(v[2]), packh2(v[3]));
    *(uint4*)(p + 4) = make_uint4(packh2(v[4]), packh2(v[5]), packh2(v[6]), packh2(v[7]));
}

__device__ __forceinline__ void oct_gather(const uint* drow, int o0, float2 v[8]){
    const uint* b = drow + LPH(o0);
    #pragma unroll
    for (int q = 0; q < 8; ++q) v[q] = unph(b[68*q]);
}

template<bool INV>
__device__ __forceinline__ void fft_wave12(uint* drow, const float2* tw, int l)
{
    WSYNC();
    {
        int a = l&7, m = l>>3;
        uint* b = drow + 68*m + a;
        float2 v[8];
        v[0] = unph(b[0]);
        #pragma unroll
        for (int j = 1; j < 8; ++j)
            v[j] = cmul(unph(b[8*j]), twz<INV>(tw, 8*a*j));
        dft8<INV>(v);
        #pragma unroll
        for (int j = 0; j < 8; ++j) b[8*j] = packh2(v[j]);
    }
    WSYNC();
    {
        uint* b = drow + l;
        float2 v[8];
        v[0] = unph(b[0]);
        #pragma unroll
        for (int q = 1; q < 8; ++q)
            v[q] = cmul(unph(b[68*q]), twz<INV>(tw, (l*q)&511));
        dft8<INV>(v);
        #pragma unroll
        for (int q = 0; q < 8; ++q) b[68*q] = packh2(v[q]);
    }
    WSYNC();
}

__global__ void k_twiddle(float2* __restrict__ twg){
    int t = blockIdx.x*256 + threadIdx.x;
    if (t < 512) {
        float s, c;
        sincosf((float)t * (-6.2831853071795864769f/512.0f), &s, &c);
        twg[t] = make_float2(c, s);
    }
}

__device__ __forceinline__ float2 twf(int idx){
    float s, c;
    sincosf((float)(idx & 511) * (-6.2831853071795864769f/512.0f), &s, &c);
    return make_float2(c, s);
}

// precompute all MFMA twiddle A-fragments; 51 blocks, one table slice each
__global__ void k_mfrag(uint4* __restrict__ fA, uint4* __restrict__ fB,
                        uint4* __restrict__ fG, uint4* __restrict__ fC)
{
    const int lane = threadIdx.x;
    const int bx = blockIdx.x;
    const int l15 = lane & 15;
    const int kb = (lane >> 4) * 8;
    if (bx < 2) {
        const int mt = bx;
        const int m = mt*16 + l15;
        uint ur[4], ui[4], un[4];
        for (int p = 0; p < 4; ++p) {
            float2 t0 = twf(16*m*(kb + 2*p));
            float2 t1 = twf(16*m*(kb + 2*p+1));
            ur[p] = packh(t0.x, t1.x);
            ui[p] = packh(t0.y, t1.y);
            un[p] = ui[p] ^ 0x80008000u;
        }
        fA[(lane*2 + mt)*3 + 0] = make_uint4(ur[0],ur[1],ur[2],ur[3]);
        fA[(lane*2 + mt)*3 + 1] = make_uint4(ui[0],ui[1],ui[2],ui[3]);
        fA[(lane*2 + mt)*3 + 2] = make_uint4(un[0],un[1],un[2],un[3]);
    } else if (bx < 18) {
        const int k2 = bx - 2;
        uint ar[4]={0,0,0,0}, ai[4]={0,0,0,0}, an[4]={0,0,0,0};
        if (lane < 32) {
            const int kk = k2 + 32*l15;
            for (int p = 0; p < 4; ++p) {
                float2 t0 = twf((kb + 2*p)*kk);
                float2 t1 = twf((kb + 2*p+1)*kk);
                ar[p] = packh(t0.x, t1.x);
                ai[p] = packh(t0.y, t1.y);
                an[p] = ai[p] ^ 0x80008000u;
            }
        }
        fB[(lane*16 + k2)*3 + 0] = make_uint4(ar[0],ar[1],ar[2],ar[3]);
        fB[(lane*16 + k2)*3 + 1] = make_uint4(ai[0],ai[1],ai[2],ai[3]);
        fB[(lane*16 + k2)*3 + 2] = make_uint4(an[0],an[1],an[2],an[3]);
    } else if (bx == 18) {
        uint gr[4]={0,0,0,0}, gi[4]={0,0,0,0}, gn[4]={0,0,0,0};
        if (lane < 32) {
            for (int p = 0; p < 4; ++p) {
                float2 t0 = twf(32*(kb + 2*p)*l15);
                float2 t1 = twf(32*(kb + 2*p+1)*l15);
                gr[p] = packh(t0.x, t1.x);
                gi[p] = packh(-t0.y, -t1.y);
                gn[p] = gi[p] ^ 0x80008000u;
            }
        }
        fG[lane*3 + 0] = make_uint4(gr[0],gr[1],gr[2],gr[3]);
        fG[lane*3 + 1] = make_uint4(gi[0],gi[1],gi[2],gi[3]);
        fG[lane*3 + 2] = make_uint4(gn[0],gn[1],gn[2],gn[3]);
    } else {
        const int t = bx - 19;
        const int n1 = t >> 1, mt = t & 1;
        const int hh = n1 + 16*(mt*16 + l15);
        uint cr[4], ci[4], cn[4];
        for (int p = 0; p < 4; ++p) {
            float2 t0 = twf(hh*(kb + 2*p));
            float2 t1 = twf(hh*(kb + 2*p+1));
            cr[p] = packh(t0.x, t1.x);
            ci[p] = packh(-t0.y, -t1.y);
            cn[p] = ci[p] ^ 0x80008000u;
        }
        fC[((lane*16 + n1)*2 + mt)*3 + 0] = make_uint4(cr[0],cr[1],cr[2],cr[3]);
        fC[((lane*16 + n1)*2 + mt)*3 + 1] = make_uint4(ci[0],ci[1],ci[2],ci[3]);
        fC[((lane*16 + n1)*2 + mt)*3 + 2] = make_uint4(cn[0],cn[1],cn[2],cn[3]);
    }
}

__global__ void k_wprep(const float* __restrict__ w, ushort* __restrict__ wtp){
    int i = blockIdx.x*256 + threadIdx.x;
    if (i < 9216) {
        int j = i & 7, l = (i>>3) & 63, m = (i>>9) & 1, tap = i >> 10;
        int co = m*16 + (l & 15), ci = ((l>>4)&3)*8 + j;
        wtp[i] = f2bf(w[(co*32 + ci)*9 + tap]);
    }
}

// ---------------- NCHW fp32 -> NHWC bf16 transpose ----------------
__global__ __launch_bounds__(256) void k_transpose(const float* __restrict__ x, ushort* __restrict__ xt){
    __shared__ ushort tl[64][36];
    const int tid = threadIdx.x;
    const int w0 = blockIdx.x*64, h = blockIdx.y, b = blockIdx.z;
    #pragma unroll
    for (int it = 0; it < 8; ++it) {
        int i = it*256 + tid, c = i >> 6, ww = i & 63;
        tl[ww][c] = f2bf(x[(((size_t)b*32 + c)*512 + h)*512 + w0 + ww]);
    }
    __syncthreads();
    const int ww = tid >> 2, c0 = (tid & 3) * 8;
    uint4 v;
    v.x = *(const uint*)&tl[ww][c0+0];
    v.y = *(const uint*)&tl[ww][c0+2];
    v.z = *(const uint*)&tl[ww][c0+4];
    v.w = *(const uint*)&tl[ww][c0+6];
    *(uint4*)(xt + ((((size_t)b*512 + h)*512 + w0 + ww)*32 + c0)) = v;
}

// ---------------- conv 3x3 via bf16 MFMA, bf16 out, fused bias + BN1 stats ----------------
__global__ __launch_bounds__(256) void k_conv_mfma(
    const ushort* __restrict__ xt, const ushort* __restrict__ wtp,
    const float* __restrict__ bias, ushort* __restrict__ out, float* __restrict__ stats)
{
    __shared__ float sred[64];
    const int tid = threadIdx.x;
    const int wid = tid >> 6, lane = tid & 63;
    const int h = blockIdx.y*4 + wid;
    const int w0 = blockIdx.x*64;
    const int b = blockIdx.z;

    short8 wa[9][2];
    #pragma unroll
    for (int tap = 0; tap < 9; ++tap)
        #pragma unroll
        for (int m = 0; m < 2; ++m)
            wa[tap][m] = *reinterpret_cast<const short8*>(wtp + ((tap*2 + m)*64 + lane)*8);

    f32x4 acc[2][4];
    #pragma unroll
    for (int m = 0; m < 2; ++m)
        #pragma unroll
        for (int n = 0; n < 4; ++n)
            acc[m][n] = (f32x4){0.f, 0.f, 0.f, 0.f};

    const int c0 = ((lane >> 4) & 3) * 8;
    const int pw = w0 + (lane & 15);
    const size_t ibase = (size_t)b * 512 * 512;

    #pragma unroll
    for (int dy = -1; dy <= 1; ++dy) {
        const int hh = h + dy;
        const bool hok = (unsigned)hh < 512u;
        #pragma unroll
        for (int dx = -1; dx <= 1; ++dx) {
            const int tap = (dy+1)*3 + (dx+1);
            short8 bfr[4];
            #pragma unroll
            for (int n = 0; n < 4; ++n) {
                const int ww = pw + n*16 + dx;
                short8 v = {0,0,0,0,0,0,0,0};
                if (hok && (unsigned)ww < 512u)
                    v = *reinterpret_cast<const short8*>(xt + ((ibase + (size_t)hh*512 + ww)*32 + c0));
                bfr[n] = v;
            }
            #pragma unroll
            for (int m = 0; m < 2; ++m)
                #pragma unroll
                for (int n = 0; n < 4; ++n)
                    acc[m][n] = __builtin_amdgcn_mfma_f32_16x16x32_bf16(wa[tap][m], bfr[n], acc[m][n], 0, 0, 0);
        }
    }

    if (tid < 64) sred[tid] = 0.f;
    __syncthreads();

    float bv[2][4];
    #pragma unroll
    for (int m = 0; m < 2; ++m)
        #pragma unroll
        for (int r = 0; r < 4; ++r)
            bv[m][r] = bias[m*16 + ((lane>>4)&3)*4 + r];

    float s8[8], q8[8];
    #pragma unroll
    for (int i = 0; i < 8; ++i) { s8[i] = 0.f; q8[i] = 0.f; }

    #pragma unroll
    for (int m = 0; m < 2; ++m) {
        #pragma unroll
        for (int n = 0; n < 4; ++n) {
            #pragma unroll
            for (int r = 0; r < 4; ++r) {
                const int co = m*16 + ((lane>>4)&3)*4 + r;
                const int ww = w0 + n*16 + (lane & 15);
                float val = acc[m][n][r] + bv[m][r];
                out[(((size_t)b*32 + co)*512 + h)*512 + ww] = f2bf(val);
                s8[m*4+r] += val;
                q8[m*4+r] += val*val;
            }
        }
    }
    #pragma unroll
    for (int i = 0; i < 8; ++i) {
        #pragma unroll
        for (int off = 1; off < 16; off <<= 1) {
            s8[i] += __shfl_xor(s8[i], off, 64);
            q8[i] += __shfl_xor(q8[i], off, 64);
        }
    }
    if ((lane & 15) == 0) {
        #pragma unroll
        for (int m = 0; m < 2; ++m)
            #pragma unroll
            for (int r = 0; r < 4; ++r) {
                const int co = m*16 + ((lane>>4)&3)*4 + r;
                atomicAdd(&sred[co], s8[m*4+r]);
                atomicAdd(&sred[32+co], q8[m*4+r]);
            }
    }
    __syncthreads();
    if (tid < 64) {
        int bin = (blockIdx.y*8 + blockIdx.x + blockIdx.z) & 63;
        atomicAdd(&stats[bin*64 + tid], sred[tid]);
    }
}

__global__ void k_finalize(const float* __restrict__ stats, int nbins, const float* __restrict__ g,
                           const float* __restrict__ bta, float* __restrict__ bnp)
{
    int c = threadIdx.x;
    if (c < 32) {
        float s = 0.f, q = 0.f;
        for (int i = 0; i < nbins; ++i) { s += stats[i*64 + c]; q += stats[i*64 + 32 + c]; }
        const float inv_n = 1.f/1048576.f;
        float mean = s * inv_n;
        float var  = q * inv_n - mean*mean;
        float sc = g[c] * rsqrtf(var + 1e-5f);
        bnp[c] = sc;
        bnp[32+c] = bta[c] - mean*sc;
    }
}

__global__ void k_finalize2(const float* __restrict__ ystats, const float* __restrict__ sstats,
                            const float* __restrict__ g, const float* __restrict__ bta,
                            float* __restrict__ bnp2)
{
    int c = threadIdx.x;
    if (c < 32) {
        float Sy = 0.f, Sy2 = 0.f, Sgg = 0.f, Sgu = 0.f, Sg0 = 0.f;
        for (int i = 0; i < 64; ++i){ Sy  += ystats[i*64 + c]; Sy2 += ystats[i*64 + 32 + c]; }
        for (int i = 0; i < 32; ++i){ Sgg += sstats[i*96 + c]; Sgu += sstats[i*96 + 32 + c]; Sg0 += sstats[i*96 + 64 + c]; }
        const float inv_n = 1.f/1048576.f;
        float Sfo  = Sg0 + Sy;
        float Sfo2 = Sgg*(1.f/512.f) + Sgu*(2.f/512.f) + Sy2;
        float mean = Sfo*inv_n;
        float var  = Sfo2*inv_n - mean*mean;
        float sc = g[c]*rsqrtf(var + 1e-5f);
        bnp2[c] = sc;
        bnp2[32+c] = bta[c] - mean*sc;
    }
}

// ---------------- row rfft: wave-local FFT (2 real rows per wave), bf16 in/out ----------------
__global__ __launch_bounds__(512) void k_rowfft_fwd(
    const ushort* __restrict__ cvo, const float* __restrict__ bnp,
    const float2* __restrict__ twg, uint* __restrict__ spec, float* __restrict__ ystats)
{
    __shared__ float2 tw[512];
    __shared__ uint d[8*ROWH];
    const int tid = threadIdx.x;
    const int h0 = blockIdx.x * 16;
    const int bc = blockIdx.y;
    const int c = bc & 31;
    ld_tw<512>(tw, twg, tid);
    __syncthreads();
    const float s1 = bnp[c], t1 = bnp[32+c];
    const int row = tid >> 6, l = tid & 63;
    const int o0 = ((l&7)<<3) | (l>>3);
    uint* drow = d + row*ROWH;
    const ushort* rp0 = cvo + ((size_t)bc*512 + h0 + 2*row)*512 + o0;
    const ushort* rp1 = rp0 + 512;
    float ls = 0.f, lsq = 0.f;
    float2 v[8];
    #pragma unroll
    for (int q = 0; q < 8; ++q) {
        float y0 = fmaxf(fmaf(bf2f(rp0[64*q]), s1, t1), 0.f);
        float y1 = fmaxf(fmaf(bf2f(rp1[64*q]), s1, t1), 0.f);
        ls += y0 + y1; lsq += y0*y0 + y1*y1;
        v[q] = make_float2(y0, y1);
    }
    dft8<false>(v);
    oct_write(drow, l, v);
    fft_wave12<false>(drow, tw, l);
    __syncthreads();
    for (int i = tid; i < 8*WF; i += 512) {
        int p = i & 7, w = i >> 3;
        float2 Z  = unph(d[p*ROWH + LPH(w)]);
        float2 Zm = unph(d[p*ROWH + LPH((512 - w) & 511)]);
        float x1r = 0.5f*(Z.x + Zm.x), x1i = 0.5f*(Z.y - Zm.y);
        float x2r = 0.5f*(Z.y + Zm.y), x2i = 0.5f*(Zm.x - Z.x);
        uint2 pk;
        pk.x = packbf(x1r, x1i);
        pk.y = packbf(x2r, x2i);
        *(uint2*)(spec + ((size_t)bc*WF + w)*512 + h0 + 2*p) = pk;
    }
    #pragma unroll
    for (int off = 32; off; off >>= 1){ ls += __shfl_down(ls, off, 64); lsq += __shfl_down(lsq, off, 64); }
    if (l == 0) {
        int bin = ((blockIdx.x << 3) + row) & 63;
        atomicAdd(&ystats[bin*64 + c], ls);
        atomicAdd(&ystats[bin*64 + 32 + c], lsq);
    }
}

// ---------------- col transform via f16 MFMA (precomputed fragments; R11 indexing) ----------------
__global__ __launch_bounds__(512) void k_colfft(uint* __restrict__ spec,
    const float* __restrict__ w1, const float* __restrict__ b1,
    const float* __restrict__ w2, const float* __restrict__ b2,
    const uint4* __restrict__ fA, const uint4* __restrict__ fB,
    const uint4* __restrict__ fG, const uint4* __restrict__ fC,
    float* __restrict__ sstats)
{
    __shared__ uint sl[32*513];
    __shared__ float wl[640];
    const int tid = threadIdx.x;
    const int lane = tid & 63, wv = tid >> 6;
    const int w = blockIdx.x, b = blockIdx.y;
    const int l15 = lane & 15, lq = lane >> 4;
    const int kb = lq * 8;

    if (tid < 128) {
        int g = tid >> 4, j = tid & 15;
        wl[g*80 + j]      = w1[g*16 + j];
        wl[g*80 + 16 + j] = w1[128 + g*16 + j];
        wl[g*80 + 32 + j] = w2[g*16 + j];
        wl[g*80 + 48 + j] = w2[128 + g*16 + j];
    } else if (tid < 160) {
        int t2 = tid - 128, g = t2 >> 2, o = t2 & 3;
        wl[g*80 + 64 + o] = b1[g*4 + o];
        wl[g*80 + 68 + o] = b1[32 + g*4 + o];
        wl[g*80 + 72 + o] = b2[g*4 + o];
        wl[g*80 + 76 + o] = b2[32 + g*4 + o];
    }
    const size_t gbase = ((size_t)b*32*WF + w) * 512;
    #pragma unroll 4
    for (int c = 0; c < 32; ++c) {
        float2 u = unpackbf(spec[gbase + (size_t)c*(WF*512) + tid]);
        sl[c*513 + tid] = packh(u.x*(1.f/512.f), u.y*(1.f/512.f));
    }
    __syncthreads();

    // ===== forward stage A (K=32)
    {
        h8 Fr[2], Fi[2], nFi[2];
        #pragma unroll
        for (int mt = 0; mt < 2; ++mt) {
            UH8 a; a.u = fA[(lane*2 + mt)*3 + 0]; Fr[mt]=a.h;
            UH8 bb; bb.u = fA[(lane*2 + mt)*3 + 1]; Fi[mt]=bb.h;
            UH8 cc; cc.u = fA[(lane*2 + mt)*3 + 2]; nFi[mt]=cc.h;
        }
        #pragma unroll
        for (int s = 0; s < 2; ++s) {
            const int n1 = wv*2 + s;
            h8 Br[2], Bi[2];
            #pragma unroll
            for (int nt = 0; nt < 2; ++nt) {
                const int base = (nt*16 + l15)*513 + n1;
                uint dd[8];
                #pragma unroll
                for (int j = 0; j < 8; ++j) dd[j] = sl[base + 16*(kb + j)];
                uint br[4], bi[4];
                #pragma unroll
                for (int p = 0; p < 4; ++p) {
                    br[p] = (dd[2*p] & 0xffffu) | (dd[2*p+1] << 16);
                    bi[p] = (dd[2*p] >> 16) | (dd[2*p+1] & 0xffff0000u);
                }
                UH8 t1_; t1_.u = make_uint4(br[0],br[1],br[2],br[3]); Br[nt]=t1_.h;
                UH8 t2_; t2_.u = make_uint4(bi[0],bi[1],bi[2],bi[3]); Bi[nt]=t2_.h;
            }
            #pragma unroll
            for (int mt = 0; mt < 2; ++mt)
            #pragma unroll
            for (int nt = 0; nt < 2; ++nt) {
                f32x4 yr = {0.f,0.f,0.f,0.f}, yi = {0.f,0.f,0.f,0.f};
                yr = __builtin_amdgcn_mfma_f32_16x16x32_f16(Fr[mt], Br[nt], yr, 0,0,0);
                yr = __builtin_amdgcn_mfma_f32_16x16x32_f16(nFi[mt], Bi[nt], yr, 0,0,0);
                yi = __builtin_amdgcn_mfma_f32_16x16x32_f16(Fr[mt], Bi[nt], yi, 0,0,0);
                yi = __builtin_amdgcn_mfma_f32_16x16x32_f16(Fi[mt], Br[nt], yi, 0,0,0);
                const int cw = (nt*16 + l15)*513 + n1;
                #pragma unroll
                for (int r = 0; r < 4; ++r)
                    sl[cw + 16*(mt*16 + lq*4 + r)] = packh(yr[r], yi[r]);
            }
        }
    }
    __syncthreads();

    // ===== forward stage B (K=16)
    #pragma unroll
    for (int s = 0; s < 4; ++s) {
        const int k2 = wv*4 + s;
        h8 Ar, Ai, nAi;
        {
            UH8 a; a.u = fB[(lane*16 + k2)*3 + 0]; Ar=a.h;
            UH8 bb; bb.u = fB[(lane*16 + k2)*3 + 1]; Ai=bb.h;
            UH8 cc; cc.u = fB[(lane*16 + k2)*3 + 2]; nAi=cc.h;
        }
        #pragma unroll
        for (int ct = 0; ct < 2; ++ct) {
            const int cb2 = (ct*16 + l15)*513 + 16*k2;
            h8 Br, Bi;
            {
                uint dd[8] = {0,0,0,0,0,0,0,0};
                if (lane < 32) {
                    #pragma unroll
                    for (int j = 0; j < 8; ++j) dd[j] = sl[cb2 + kb + j];
                }
                uint br[4], bi[4];
                #pragma unroll
                for (int p = 0; p < 4; ++p) {
                    br[p] = (dd[2*p] & 0xffffu) | (dd[2*p+1] << 16);
                    bi[p] = (dd[2*p] >> 16) | (dd[2*p+1] & 0xffff0000u);
                }
                UH8 t1_; t1_.u = make_uint4(br[0],br[1],br[2],br[3]); Br=t1_.h;
                UH8 t2_; t2_.u = make_uint4(bi[0],bi[1],bi[2],bi[3]); Bi=t2_.h;
            }
            f32x4 xr = {0.f,0.f,0.f,0.f}, xi = {0.f,0.f,0.f,0.f};
            xr = __builtin_amdgcn_mfma_f32_16x16x32_f16(Ar, Br, xr, 0,0,0);
            xr = __builtin_amdgcn_mfma_f32_16x16x32_f16(nAi, Bi, xr, 0,0,0);
            xi = __builtin_amdgcn_mfma_f32_16x16x32_f16(Ar, Bi, xi, 0,0,0);
            xi = __builtin_amdgcn_mfma_f32_16x16x32_f16(Ai, Br, xi, 0,0,0);
            #pragma unroll
            for (int r = 0; r < 4; ++r)
                sl[cb2 + lq*4 + r] = packh(xr[r], xi[r]);
        }
    }
    __syncthreads();

    // ===== MLP + softshrink + gate (pointwise)
    #pragma unroll
    for (int g = 0; g < 8; ++g) {
        const float* wk = wl + g*80;
        float xr[4], xi[4];
        #pragma unroll
        for (int i = 0; i < 4; ++i) {
            float2 v = unph(sl[(4*g+i)*513 + tid]);
            xr[i] = v.x; xi[i] = v.y;
        }
        float o1r[4], o1i[4];
        #pragma unroll
        for (int o = 0; o < 4; ++o) {
            float sr = wk[64+o], si = wk[68+o];
            #pragma unroll
            for (int i = 0; i < 4; ++i) {
                float wr = wk[i*4+o], wi = wk[16 + i*4+o];
                sr += xr[i]*wr - xi[i]*wi;
                si += xi[i]*wr + xr[i]*wi;
            }
            o1r[o] = fmaxf(sr, 0.f);
            o1i[o] = fmaxf(si, 0.f);
        }
        #pragma unroll
        for (int o = 0; o < 4; ++o) {
            float sr = wk[72+o], si = wk[76+o];
            #pragma unroll
            for (int i = 0; i < 4; ++i) {
                float wr = wk[32 + i*4+o], wi = wk[48 + i*4+o];
                sr += o1r[i]*wr - o1i[i]*wi;
                si += o1i[i]*wr + o1r[i]*wi;
            }
            sr = (sr > LAM) ? sr - LAM : ((sr < -LAM) ? sr + LAM : 0.f);
            si = (si > LAM) ? si - LAM : ((si < -LAM) ? si + LAM : 0.f);
            sl[(4*g+o)*513 + tid] = packh(sr*xr[o] - si*xi[o], sr*xi[o] + si*xr[o]);
        }
    }
    __syncthreads();

    // ===== inverse stage 1 (K=16)
    {
        h8 Gr, Gi, nGi;
        {
            UH8 a; a.u = fG[lane*3 + 0]; Gr=a.h;
            UH8 bb; bb.u = fG[lane*3 + 1]; Gi=bb.h;
            UH8 cc; cc.u = fG[lane*3 + 2]; nGi=cc.h;
        }
        #pragma unroll
        for (int s = 0; s < 4; ++s) {
            const int k2 = wv*4 + s;
            #pragma unroll
            for (int ct = 0; ct < 2; ++ct) {
                const int cb2 = (ct*16 + l15)*513 + 16*k2;
                h8 Br, Bi;
                {
                    uint dd[8] = {0,0,0,0,0,0,0,0};
                    if (lane < 32) {
                        #pragma unroll
                        for (int j = 0; j < 8; ++j) dd[j] = sl[cb2 + kb + j];
                    }
                    uint br[4], bi[4];
                    #pragma unroll
                    for (int p = 0; p < 4; ++p) {
                        br[p] = (dd[2*p] & 0xffffu) | (dd[2*p+1] << 16);
                        bi[p] = (dd[2*p] >> 16) | (dd[2*p+1] & 0xffff0000u);
                    }
                    UH8 t1_; t1_.u = make_uint4(br[0],br[1],br[2],br[3]); Br=t1_.h;
                    UH8 t2_; t2_.u = make_uint4(bi[0],bi[1],bi[2],bi[3]); Bi=t2_.h;
                }
                f32x4 yr = {0.f,0.f,0.f,0.f}, yi = {0.f,0.f,0.f,0.f};
                yr = __builtin_amdgcn_mfma_f32_16x16x32_f16(Gr, Br, yr, 0,0,0);
                yr = __builtin_amdgcn_mfma_f32_16x16x32_f16(nGi, Bi, yr, 0,0,0);
                yi = __builtin_amdgcn_mfma_f32_16x16x32_f16(Gr, Bi, yi, 0,0,0);
                yi = __builtin_amdgcn_mfma_f32_16x16x32_f16(Gi, Br, yi, 0,0,0);
                #pragma unroll
                for (int r = 0; r < 4; ++r)
                    sl[cb2 + lq*4 + r] = packh(yr[r], yi[r]);
            }
        }
    }
    __syncthreads();

    // ===== inverse stage 2 (K=32)
    #pragma unroll
    for (int s = 0; s < 2; ++s) {
        const int n1 = wv*2 + s;
        h8 Cr[2], Ci[2], nCi[2];
        #pragma unroll
        for (int mt = 0; mt < 2; ++mt) {
            UH8 a; a.u = fC[((lane*16 + n1)*2 + mt)*3 + 0]; Cr[mt]=a.h;
            UH8 bb; bb.u = fC[((lane*16 + n1)*2 + mt)*3 + 1]; Ci[mt]=bb.h;
            UH8 cc; cc.u = fC[((lane*16 + n1)*2 + mt)*3 + 2]; nCi[mt]=cc.h;
        }
        h8 Br[2], Bi[2];
        #pragma unroll
        for (int nt = 0; nt < 2; ++nt) {
            const int base = (nt*16 + l15)*513 + n1;
            uint dd[8];
            #pragma unroll
            for (int j = 0; j < 8; ++j) dd[j] = sl[base + 16*(kb + j)];
            uint br[4], bi[4];
            #pragma unroll
            for (int p = 0; p < 4; ++p) {
                br[p] = (dd[2*p] & 0xffffu) | (dd[2*p+1] << 16);
                bi[p] = (dd[2*p] >> 16) | (dd[2*p+1] & 0xffff0000u);
            }
            UH8 t1_; t1_.u = make_uint4(br[0],br[1],br[2],br[3]); Br[nt]=t1_.h;
            UH8 t2_; t2_.u = make_uint4(bi[0],bi[1],bi[2],bi[3]); Bi[nt]=t2_.h;
        }
        #pragma unroll
        for (int mt = 0; mt < 2; ++mt)
        #pragma unroll
        for (int nt = 0; nt < 2; ++nt) {
            f32x4 xr = {0.f,0.f,0.f,0.f}, xi = {0.f,0.f,0.f,0.f};
            xr = __builtin_amdgcn_mfma_f32_16x16x32_f16(Cr[mt], Br[nt], xr, 0,0,0);
            xr = __builtin_amdgcn_mfma_f32_16x16x32_f16(nCi[mt], Bi[nt], xr, 0,0,0);
            xi = __builtin_amdgcn_mfma_f32_16x16x32_f16(Cr[mt], Bi[nt], xi, 0,0,0);
            xi = __builtin_amdgcn_mfma_f32_16x16x32_f16(Ci[mt], Br[nt], xi, 0,0,0);
            const int cw = (nt*16 + l15)*513 + n1;
            #pragma unroll
            for (int r = 0; r < 4; ++r)
                sl[cw + 16*(mt*16 + lq*4 + r)] = packh(xr[r], xi[r]);
        }
    }
    __syncthreads();

    // ===== epilogue: bf16 write-back + Parseval sums
    const bool edge = (w == 0) || (w == 256);
    #pragma unroll
    for (int i = 0; i < 4; ++i) {
        const int c = wv*4 + i;
        const size_t cb = gbase + (size_t)c*(WF*512);
        float fgg = 0.f, fgu = 0.f, fg0 = 0.f;
        #pragma unroll
        for (int it = 0; it < 4; ++it) {
            const int pos = it*128 + 2*lane;
            uint2 dv;
            dv.x = sl[c*513 + pos];
            dv.y = sl[c*513 + pos + 1];
            float2 z0 = unph(dv.x), z1 = unph(dv.y);
            uint2 up = *(const uint2*)(spec + cb + pos);
            float2 u0 = unpackbf(up.x), u1 = unpackbf(up.y);
            uint2 gp;
            gp.x = packbf(z0.x, z0.y);
            gp.y = packbf(z1.x, z1.y);
            *(uint2*)(spec + cb + pos) = gp;
            float2 g0 = unpackbf(gp.x), g1 = unpackbf(gp.y);
            if (edge) {
                fgg += g0.x*g0.x + g1.x*g1.x;
                fgu += g0.x*u0.x + g1.x*u1.x;
                if (w == 0) fg0 += g0.x + g1.x;
            } else {
                fgg += 2.f*(g0.x*g0.x + g0.y*g0.y + g1.x*g1.x + g1.y*g1.y);
                fgu += 2.f*(g0.x*u0.x + g0.y*u0.y + g1.x*u1.x + g1.y*u1.y);
            }
        }
        #pragma unroll
        for (int off = 32; off; off >>= 1){
            fgg += __shfl_down(fgg, off, 64);
            fgu += __shfl_down(fgu, off, 64);
            fg0 += __shfl_down(fg0, off, 64);
        }
        if (lane == 0) {
            const int kk = c >> 2, ch = c & 3;
            const int bin = (w + b*8 + kk) & 31;
            atomicAdd(&sstats[bin*96 + kk*4 + ch], fgg);
            atomicAdd(&sstats[bin*96 + 32 + kk*4 + ch], fgu);
            if (w == 0) atomicAdd(&sstats[bin*96 + 64 + kk*4 + ch], fg0);
        }
    }
}

// ---------------- row irfft: wave-local inverse FFT + BN2 + final ReLU ----------------
__global__ __launch_bounds__(512) void k_rowfft_inv(
    const uint* __restrict__ spec, const ushort* __restrict__ cvo,
    const float* __restrict__ bnp, const float* __restrict__ bnp2,
    const float2* __restrict__ twg, float* __restrict__ out)
{
    __shared__ float2 tw[512];
    __shared__ uint d[8*ROWH];
    const int tid = threadIdx.x;
    const int h0 = blockIdx.x * 16;
    const int bc = blockIdx.y;
    const int c = bc & 31;
    ld_tw<512>(tw, twg, tid);
    for (int i = tid; i < 8*WF; i += 512) {
        int p = i & 7, w = i >> 3;
        uint2 pk = *(const uint2*)(spec + ((size_t)bc*WF + w)*512 + h0 + 2*p);
        float2 X1 = unpackbf(pk.x), X2 = unpackbf(pk.y);
        if (w == 0 || w == 256) { X1.y = 0.f; X2.y = 0.f; }
        const float s = 1.f/512.f;
        d[p*ROWH + LPH(w)] = packh((X1.x - X2.y)*s, (X1.y + X2.x)*s);
        if ((unsigned)(w - 1) < 255u)
            d[p*ROWH + LPH(512 - w)] = packh((X1.x + X2.y)*s, (X2.x - X1.y)*s);
    }
    __syncthreads();
    const int row = tid >> 6, l = tid & 63;
    const int o0 = ((l&7)<<3) | (l>>3);
    uint* drow = d + row*ROWH;
    {
        float2 v[8];
        oct_gather(drow, o0, v);
        dft8<true>(v);
        WSYNC();
        oct_write(drow, l, v);
    }
    fft_wave12<true>(drow, tw, l);
    const float s1 = bnp[c],  t1 = bnp[32+c];
    const float s2 = bnp2[c], t2 = bnp2[32+c];
    const size_t gbase = ((size_t)bc*512 + h0 + 2*row)*512;
    #pragma unroll
    for (int q = 0; q < 8; ++q) {
        const int col = q*64 + l;
        float2 v = unph(drow[LPH(col)]);
        float y0 = fmaxf(fmaf(bf2f(cvo[gbase + col]), s1, t1), 0.f);
        float fo0 = v.x + y0;
        out[gbase + col] = fmaxf(y0 + fmaf(fo0, s2, t2), 0.f);
        float y1 = fmaxf(fmaf(bf2f(cvo[gbase + 512 + col]), s1, t1), 0.f);
        float fo1 = v.y + y1;
        out[gbase + 512 + col] = fmaxf(y1 + fmaf(fo1, s2, t2), 0.f);
    }
}

extern "C" void kernel_launch(void* const* d_in, const int* in_sizes, int n_in,
                              void* d_out, int out_size, void* d_ws, size_t ws_size,
                              hipStream_t stream)
{
    const float* x      = (const float*)d_in[0];
    const float* conv_w = (const float*)d_in[1];
    const float* conv_b = (const float*)d_in[2];
    const float* bn1g   = (const float*)d_in[3];
    const float* bn1b   = (const float*)d_in[4];
    const float* w1     = (const float*)d_in[5];
    const float* b1     = (const float*)d_in[6];
    const float* w2     = (const float*)d_in[7];
    const float* b2     = (const float*)d_in[8];
    const float* bn2g   = (const float*)d_in[9];
    const float* bn2b   = (const float*)d_in[10];
    float* out = (float*)d_out;

    char* ws = (char*)d_ws;
    uint*   spec  = (uint*)ws;                              // 67,371,008 B (bf16 pairs)
    ushort* xt    = (ushort*)ws;                            // aliases spec (dead before spec written)
    ushort* cvo   = (ushort*)(ws + 67371008);               // 67,108,864 B (bf16)
    ushort* wtp   = (ushort*)(ws + 67371008 + 67108864);    // 18,432 B
    float*  stats = (float*)(ws + 67371008 + 67108864 + 18432);
    float* stats1 = stats;             // 4096 f (bn1 bins)
    float* ystats = stats + 4096;      // 4096 f
    float* sstats = stats + 8192;      // 3072 f
    float* bnp1   = stats + 11264;     // 64 f
    float* bnp2   = stats + 11328;     // 64 f
    float2* twg   = (float2*)(stats + 11392); // 512 float2 (ends at stats+12416)
    uint4* fA = (uint4*)(stats + 12416);      // 384 uint4
    uint4* fB = fA + 384;                     // 3072 uint4
    uint4* fG = fB + 3072;                    // 192 uint4
    uint4* fC = fG + 192;                     // 6144 uint4

    (void)hipMemsetAsync(stats, 0, 11264*sizeof(float), stream);
    k_twiddle<<<2, 256, 0, stream>>>(twg);
    k_mfrag<<<51, 64, 0, stream>>>(fA, fB, fG, fC);
    k_wprep<<<36, 256, 0, stream>>>(conv_w, wtp);
    k_transpose<<<dim3(8,512,4), 256, 0, stream>>>(x, xt);
    k_conv_mfma<<<dim3(8,128,4), 256, 0, stream>>>(xt, wtp, conv_b, cvo, stats1);
    k_finalize<<<1, 64, 0, stream>>>(stats1, 64, bn1g, bn1b, bnp1);
    k_rowfft_fwd<<<dim3(32,128), 512, 0, stream>>>(cvo, bnp1, twg, spec, ystats);
    k_colfft<<<dim3(257,4), 512, 0, stream>>>(spec, w1, b1, w2, b2, fA, fB, fG, fC, sstats);
    k_finalize2<<<1, 64, 0, stream>>>(ystats, sstats, bn2g, bn2b, bnp2);
    k_rowfft_inv<<<dim3(32,128), 512, 0, stream>>>(spec, cvo, bnp1, bnp2, twg, out);
}

// Round 15
// 327.549 us; speedup vs baseline: 1.1878x; 1.0085x over previous
//
#include <hip/hip_runtime.h>

#define WF 257
#define LAM 0.01f
#define ROWH 540
#define LPH(i) ((i) + (((i)>>6)<<2))

#define WSYNC() do { asm volatile("" ::: "memory"); __builtin_amdgcn_wave_barrier(); asm volatile("" ::: "memory"); } while(0)

typedef __attribute__((ext_vector_type(8))) short short8;
typedef __attribute__((ext_vector_type(4))) float f32x4;
typedef __attribute__((ext_vector_type(2))) __fp16 h2v;
typedef __attribute__((ext_vector_type(8))) __fp16 h8;

union UH8 { uint4 u; h8 h; };

__device__ __forceinline__ ushort f2bf(float f){
    unsigned u = __float_as_uint(f);
    unsigned r = (u + 0x7fffu + ((u >> 16) & 1u)) >> 16;
    return (ushort)r;
}
__device__ __forceinline__ float bf2f(ushort u){ return __uint_as_float((uint)u << 16); }
__device__ __forceinline__ uint packbf(float a, float b){
    return (uint)f2bf(a) | ((uint)f2bf(b) << 16);
}
__device__ __forceinline__ float2 unpackbf(uint u){
    return make_float2(__uint_as_float(u << 16), __uint_as_float(u & 0xffff0000u));
}
__device__ __forceinline__ uint packh(float a, float b){
    h2v h;
    h[0] = (__fp16)a;
    h[1] = (__fp16)b;
    return *(uint*)&h;
}
__device__ __forceinline__ uint packh2(float2 v){ return packh(v.x, v.y); }
__device__ __forceinline__ float2 unph(uint u){
    h2v h = *(h2v*)&u;
    return make_float2((float)h[0], (float)h[1]);
}

__device__ __forceinline__ float2 cmul(float2 a, float2 b){
    return make_float2(a.x*b.x - a.y*b.y, a.x*b.y + a.y*b.x);
}
__device__ __forceinline__ float2 cadd(float2 a, float2 b){ return make_float2(a.x+b.x, a.y+b.y); }
__device__ __forceinline__ float2 csub(float2 a, float2 b){ return make_float2(a.x-b.x, a.y-b.y); }

template<int NTHREADS>
__device__ __forceinline__ void ld_tw(float2* tw, const float2* __restrict__ twg, int tid){
    for (int t = tid; t < 256; t += NTHREADS)
        ((float4*)tw)[t] = ((const float4*)twg)[t];
}

template<bool INV>
__device__ __forceinline__ float2 twz(const float2* tw, int idx){
    float2 w = tw[idx];
    if (INV) w.y = -w.y;
    return w;
}

template<bool INV>
__device__ __forceinline__ void dft8(float2 v[8]) {
    const float R = 0.70710678118654752f;
    float2 y0=v[0], y1=v[4], y2=v[2], y3=v[6], y4=v[1], y5=v[5], y6=v[3], y7=v[7];
    float2 t;
    t=y1; y1=csub(y0,t); y0=cadd(y0,t);
    t=y3; y3=csub(y2,t); y2=cadd(y2,t);
    t=y5; y5=csub(y4,t); y4=cadd(y4,t);
    t=y7; y7=csub(y6,t); y6=cadd(y6,t);
    t=y2; y2=csub(y0,t); y0=cadd(y0,t);
    t = INV ? make_float2(-y3.y, y3.x) : make_float2(y3.y, -y3.x);
    y3=csub(y1,t); y1=cadd(y1,t);
    t=y6; y6=csub(y4,t); y4=cadd(y4,t);
    t = INV ? make_float2(-y7.y, y7.x) : make_float2(y7.y, -y7.x);
    y7=csub(y5,t); y5=cadd(y5,t);
    t=y4; y4=csub(y0,t); y0=cadd(y0,t);
    { float2 w8 = INV ? make_float2(R, R) : make_float2(R,-R);
      t=cmul(y5,w8); y5=csub(y1,t); y1=cadd(y1,t); }
    t = INV ? make_float2(-y6.y, y6.x) : make_float2(y6.y, -y6.x);
    y6=csub(y2,t); y2=cadd(y2,t);
    { float2 w8 = INV ? make_float2(-R, R) : make_float2(-R,-R);
      t=cmul(y7,w8); y7=csub(y3,t); y3=cadd(y3,t); }
    v[0]=y0; v[1]=y1; v[2]=y2; v[3]=y3; v[4]=y4; v[5]=y5; v[6]=y6; v[7]=y7;
}

__device__ __forceinline__ void oct_write(uint* drow, int l, const float2 v[8]){
    uint* p = drow + LPH(8*l);
    *(uint4*)p       = make_uint4(packh2(v[0]), packh2(v[1]), packh2(v[2]), packh2(v[3]));
    *(uint4*)(p + 4) = make_uint4(packh2(v[4]), packh2(v[5]), packh2(v[6]), packh2(v[7]));
}

__device__ __forceinline__ void oct_gather(const uint* drow, int o0, float2 v[8]){
    const uint* b = drow + LPH(o0);
    #pragma unroll
    for (int q = 0; q < 8; ++q) v[q] = unph(b[68*q]);
}

template<bool INV>
__device__ __forceinline__ void fft_wave12(uint* drow, const float2* tw, int l)
{
    WSYNC();
    {
        int a = l&7, m = l>>3;
        uint* b = drow + 68*m + a;
        float2 v[8];
        v[0] = unph(b[0]);
        #pragma unroll
        for (int j = 1; j < 8; ++j)
            v[j] = cmul(unph(b[8*j]), twz<INV>(tw, 8*a*j));
        dft8<INV>(v);
        #pragma unroll
        for (int j = 0; j < 8; ++j) b[8*j] = packh2(v[j]);
    }
    WSYNC();
    {
        uint* b = drow + l;
        float2 v[8];
        v[0] = unph(b[0]);
        #pragma unroll
        for (int q = 1; q < 8; ++q)
            v[q] = cmul(unph(b[68*q]), twz<INV>(tw, (l*q)&511));
        dft8<INV>(v);
        #pragma unroll
        for (int q = 0; q < 8; ++q) b[68*q] = packh2(v[q]);
    }
    WSYNC();
}

__global__ void k_twiddle(float2* __restrict__ twg){
    int t = blockIdx.x*256 + threadIdx.x;
    if (t < 512) {
        float s, c;
        sincosf((float)t * (-6.2831853071795864769f/512.0f), &s, &c);
        twg[t] = make_float2(c, s);
    }
}

__device__ __forceinline__ float2 twf(int idx){
    float s, c;
    sincosf((float)(idx & 511) * (-6.2831853071795864769f/512.0f), &s, &c);
    return make_float2(c, s);
}

// precompute all MFMA twiddle A-fragments; 67 blocks, one table slice each.
// fB covers k2 in [0,32) (stride 32) -- R13/R14 had only [0,16): stage-B k2>=16 read wrong fragments.
__global__ void k_mfrag(uint4* __restrict__ fA, uint4* __restrict__ fB,
                        uint4* __restrict__ fG, uint4* __restrict__ fC)
{
    const int lane = threadIdx.x;
    const int bx = blockIdx.x;
    const int l15 = lane & 15;
    const int kb = (lane >> 4) * 8;
    if (bx < 2) {
        const int mt = bx;
        const int m = mt*16 + l15;
        uint ur[4], ui[4], un[4];
        for (int p = 0; p < 4; ++p) {
            float2 t0 = twf(16*m*(kb + 2*p));
            float2 t1 = twf(16*m*(kb + 2*p+1));
            ur[p] = packh(t0.x, t1.x);
            ui[p] = packh(t0.y, t1.y);
            un[p] = ui[p] ^ 0x80008000u;
        }
        fA[(lane*2 + mt)*3 + 0] = make_uint4(ur[0],ur[1],ur[2],ur[3]);
        fA[(lane*2 + mt)*3 + 1] = make_uint4(ui[0],ui[1],ui[2],ui[3]);
        fA[(lane*2 + mt)*3 + 2] = make_uint4(un[0],un[1],un[2],un[3]);
    } else if (bx < 34) {
        const int k2 = bx - 2;                      // [0,32)
        uint ar[4]={0,0,0,0}, ai[4]={0,0,0,0}, an[4]={0,0,0,0};
        if (lane < 32) {
            const int kk = k2 + 32*l15;
            for (int p = 0; p < 4; ++p) {
                float2 t0 = twf((kb + 2*p)*kk);
                float2 t1 = twf((kb + 2*p+1)*kk);
                ar[p] = packh(t0.x, t1.x);
                ai[p] = packh(t0.y, t1.y);
                an[p] = ai[p] ^ 0x80008000u;
            }
        }
        fB[(lane*32 + k2)*3 + 0] = make_uint4(ar[0],ar[1],ar[2],ar[3]);
        fB[(lane*32 + k2)*3 + 1] = make_uint4(ai[0],ai[1],ai[2],ai[3]);
        fB[(lane*32 + k2)*3 + 2] = make_uint4(an[0],an[1],an[2],an[3]);
    } else if (bx == 34) {
        uint gr[4]={0,0,0,0}, gi[4]={0,0,0,0}, gn[4]={0,0,0,0};
        if (lane < 32) {
            for (int p = 0; p < 4; ++p) {
                float2 t0 = twf(32*(kb + 2*p)*l15);
                float2 t1 = twf(32*(kb + 2*p+1)*l15);
                gr[p] = packh(t0.x, t1.x);
                gi[p] = packh(-t0.y, -t1.y);
                gn[p] = gi[p] ^ 0x80008000u;
            }
        }
        fG[lane*3 + 0] = make_uint4(gr[0],gr[1],gr[2],gr[3]);
        fG[lane*3 + 1] = make_uint4(gi[0],gi[1],gi[2],gi[3]);
        fG[lane*3 + 2] = make_uint4(gn[0],gn[1],gn[2],gn[3]);
    } else {
        const int t = bx - 35;
        const int n1 = t >> 1, mt = t & 1;
        const int hh = n1 + 16*(mt*16 + l15);
        uint cr[4], ci[4], cn[4];
        for (int p = 0; p < 4; ++p) {
            float2 t0 = twf(hh*(kb + 2*p));
            float2 t1 = twf(hh*(kb + 2*p+1));
            cr[p] = packh(t0.x, t1.x);
            ci[p] = packh(-t0.y, -t1.y);
            cn[p] = ci[p] ^ 0x80008000u;
        }
        fC[((lane*16 + n1)*2 + mt)*3 + 0] = make_uint4(cr[0],cr[1],cr[2],cr[3]);
        fC[((lane*16 + n1)*2 + mt)*3 + 1] = make_uint4(ci[0],ci[1],ci[2],ci[3]);
        fC[((lane*16 + n1)*2 + mt)*3 + 2] = make_uint4(cn[0],cn[1],cn[2],cn[3]);
    }
}

__global__ void k_wprep(const float* __restrict__ w, ushort* __restrict__ wtp){
    int i = blockIdx.x*256 + threadIdx.x;
    if (i < 9216) {
        int j = i & 7, l = (i>>3) & 63, m = (i>>9) & 1, tap = i >> 10;
        int co = m*16 + (l & 15), ci = ((l>>4)&3)*8 + j;
        wtp[i] = f2bf(w[(co*32 + ci)*9 + tap]);
    }
}

// ---------------- NCHW fp32 -> NHWC bf16 transpose ----------------
__global__ __launch_bounds__(256) void k_transpose(const float* __restrict__ x, ushort* __restrict__ xt){
    __shared__ ushort tl[64][36];
    const int tid = threadIdx.x;
    const int w0 = blockIdx.x*64, h = blockIdx.y, b = blockIdx.z;
    #pragma unroll
    for (int it = 0; it < 8; ++it) {
        int i = it*256 + tid, c = i >> 6, ww = i & 63;
        tl[ww][c] = f2bf(x[(((size_t)b*32 + c)*512 + h)*512 + w0 + ww]);
    }
    __syncthreads();
    const int ww = tid >> 2, c0 = (tid & 3) * 8;
    uint4 v;
    v.x = *(const uint*)&tl[ww][c0+0];
    v.y = *(const uint*)&tl[ww][c0+2];
    v.z = *(const uint*)&tl[ww][c0+4];
    v.w = *(const uint*)&tl[ww][c0+6];
    *(uint4*)(xt + ((((size_t)b*512 + h)*512 + w0 + ww)*32 + c0)) = v;
}

// ---------------- conv 3x3 via bf16 MFMA, bf16 out, fused bias + BN1 stats ----------------
__global__ __launch_bounds__(256) void k_conv_mfma(
    const ushort* __restrict__ xt, const ushort* __restrict__ wtp,
    const float* __restrict__ bias, ushort* __restrict__ out, float* __restrict__ stats)
{
    __shared__ float sred[64];
    const int tid = threadIdx.x;
    const int wid = tid >> 6, lane = tid & 63;
    const int h = blockIdx.y*4 + wid;
    const int w0 = blockIdx.x*64;
    const int b = blockIdx.z;

    short8 wa[9][2];
    #pragma unroll
    for (int tap = 0; tap < 9; ++tap)
        #pragma unroll
        for (int m = 0; m < 2; ++m)
            wa[tap][m] = *reinterpret_cast<const short8*>(wtp + ((tap*2 + m)*64 + lane)*8);

    f32x4 acc[2][4];
    #pragma unroll
    for (int m = 0; m < 2; ++m)
        #pragma unroll
        for (int n = 0; n < 4; ++n)
            acc[m][n] = (f32x4){0.f, 0.f, 0.f, 0.f};

    const int c0 = ((lane >> 4) & 3) * 8;
    const int pw = w0 + (lane & 15);
    const size_t ibase = (size_t)b * 512 * 512;

    #pragma unroll
    for (int dy = -1; dy <= 1; ++dy) {
        const int hh = h + dy;
        const bool hok = (unsigned)hh < 512u;
        #pragma unroll
        for (int dx = -1; dx <= 1; ++dx) {
            const int tap = (dy+1)*3 + (dx+1);
            short8 bfr[4];
            #pragma unroll
            for (int n = 0; n < 4; ++n) {
                const int ww = pw + n*16 + dx;
                short8 v = {0,0,0,0,0,0,0,0};
                if (hok && (unsigned)ww < 512u)
                    v = *reinterpret_cast<const short8*>(xt + ((ibase + (size_t)hh*512 + ww)*32 + c0));
                bfr[n] = v;
            }
            #pragma unroll
            for (int m = 0; m < 2; ++m)
                #pragma unroll
                for (int n = 0; n < 4; ++n)
                    acc[m][n] = __builtin_amdgcn_mfma_f32_16x16x32_bf16(wa[tap][m], bfr[n], acc[m][n], 0, 0, 0);
        }
    }

    if (tid < 64) sred[tid] = 0.f;
    __syncthreads();

    float bv[2][4];
    #pragma unroll
    for (int m = 0; m < 2; ++m)
        #pragma unroll
        for (int r = 0; r < 4; ++r)
            bv[m][r] = bias[m*16 + ((lane>>4)&3)*4 + r];

    float s8[8], q8[8];
    #pragma unroll
    for (int i = 0; i < 8; ++i) { s8[i] = 0.f; q8[i] = 0.f; }

    #pragma unroll
    for (int m = 0; m < 2; ++m) {
        #pragma unroll
        for (int n = 0; n < 4; ++n) {
            #pragma unroll
            for (int r = 0; r < 4; ++r) {
                const int co = m*16 + ((lane>>4)&3)*4 + r;
                const int ww = w0 + n*16 + (lane & 15);
                float val = acc[m][n][r] + bv[m][r];
                out[(((size_t)b*32 + co)*512 + h)*512 + ww] = f2bf(val);
                s8[m*4+r] += val;
                q8[m*4+r] += val*val;
            }
        }
    }
    #pragma unroll
    for (int i = 0; i < 8; ++i) {
        #pragma unroll
        for (int off = 1; off < 16; off <<= 1) {
            s8[i] += __shfl_xor(s8[i], off, 64);
            q8[i] += __shfl_xor(q8[i], off, 64);
        }
    }
    if ((lane & 15) == 0) {
        #pragma unroll
        for (int m = 0; m < 2; ++m)
            #pragma unroll
            for (int r = 0; r < 4; ++r) {
                const int co = m*16 + ((lane>>4)&3)*4 + r;
                atomicAdd(&sred[co], s8[m*4+r]);
                atomicAdd(&sred[32+co], q8[m*4+r]);
            }
    }
    __syncthreads();
    if (tid < 64) {
        int bin = (blockIdx.y*8 + blockIdx.x + blockIdx.z) & 63;
        atomicAdd(&stats[bin*64 + tid], sred[tid]);
    }
}

__global__ void k_finalize(const float* __restrict__ stats, int nbins, const float* __restrict__ g,
                           const float* __restrict__ bta, float* __restrict__ bnp)
{
    int c = threadIdx.x;
    if (c < 32) {
        float s = 0.f, q = 0.f;
        for (int i = 0; i < nbins; ++i) { s += stats[i*64 + c]; q += stats[i*64 + 32 + c]; }
        const float inv_n = 1.f/1048576.f;
        float mean = s * inv_n;
        float var  = q * inv_n - mean*mean;
        float sc = g[c] * rsqrtf(var + 1e-5f);
        bnp[c] = sc;
        bnp[32+c] = bta[c] - mean*sc;
    }
}

__global__ void k_finalize2(const float* __restrict__ ystats, const float* __restrict__ sstats,
                            const float* __restrict__ g, const float* __restrict__ bta,
                            float* __restrict__ bnp2)
{
    int c = threadIdx.x;
    if (c < 32) {
        float Sy = 0.f, Sy2 = 0.f, Sgg = 0.f, Sgu = 0.f, Sg0 = 0.f;
        for (int i = 0; i < 64; ++i){ Sy  += ystats[i*64 + c]; Sy2 += ystats[i*64 + 32 + c]; }
        for (int i = 0; i < 32; ++i){ Sgg += sstats[i*96 + c]; Sgu += sstats[i*96 + 32 + c]; Sg0 += sstats[i*96 + 64 + c]; }
        const float inv_n = 1.f/1048576.f;
        float Sfo  = Sg0 + Sy;
        float Sfo2 = Sgg*(1.f/512.f) + Sgu*(2.f/512.f) + Sy2;
        float mean = Sfo*inv_n;
        float var  = Sfo2*inv_n - mean*mean;
        float sc = g[c]*rsqrtf(var + 1e-5f);
        bnp2[c] = sc;
        bnp2[32+c] = bta[c] - mean*sc;
    }
}

// ---------------- row rfft: wave-local FFT (2 real rows per wave), bf16 in/out ----------------
__global__ __launch_bounds__(512) void k_rowfft_fwd(
    const ushort* __restrict__ cvo, const float* __restrict__ bnp,
    const float2* __restrict__ twg, uint* __restrict__ spec, float* __restrict__ ystats)
{
    __shared__ float2 tw[512];
    __shared__ uint d[8*ROWH];
    const int tid = threadIdx.x;
    const int h0 = blockIdx.x * 16;
    const int bc = blockIdx.y;
    const int c = bc & 31;
    ld_tw<512>(tw, twg, tid);
    __syncthreads();
    const float s1 = bnp[c], t1 = bnp[32+c];
    const int row = tid >> 6, l = tid & 63;
    const int o0 = ((l&7)<<3) | (l>>3);
    uint* drow = d + row*ROWH;
    const ushort* rp0 = cvo + ((size_t)bc*512 + h0 + 2*row)*512 + o0;
    const ushort* rp1 = rp0 + 512;
    float ls = 0.f, lsq = 0.f;
    float2 v[8];
    #pragma unroll
    for (int q = 0; q < 8; ++q) {
        float y0 = fmaxf(fmaf(bf2f(rp0[64*q]), s1, t1), 0.f);
        float y1 = fmaxf(fmaf(bf2f(rp1[64*q]), s1, t1), 0.f);
        ls += y0 + y1; lsq += y0*y0 + y1*y1;
        v[q] = make_float2(y0, y1);
    }
    dft8<false>(v);
    oct_write(drow, l, v);
    fft_wave12<false>(drow, tw, l);
    __syncthreads();
    for (int i = tid; i < 8*WF; i += 512) {
        int p = i & 7, w = i >> 3;
        float2 Z  = unph(d[p*ROWH + LPH(w)]);
        float2 Zm = unph(d[p*ROWH + LPH((512 - w) & 511)]);
        float x1r = 0.5f*(Z.x + Zm.x), x1i = 0.5f*(Z.y - Zm.y);
        float x2r = 0.5f*(Z.y + Zm.y), x2i = 0.5f*(Zm.x - Z.x);
        uint2 pk;
        pk.x = packbf(x1r, x1i);
        pk.y = packbf(x2r, x2i);
        *(uint2*)(spec + ((size_t)bc*WF + w)*512 + h0 + 2*p) = pk;
    }
    #pragma unroll
    for (int off = 32; off; off >>= 1){ ls += __shfl_down(ls, off, 64); lsq += __shfl_down(lsq, off, 64); }
    if (l == 0) {
        int bin = ((blockIdx.x << 3) + row) & 63;
        atomicAdd(&ystats[bin*64 + c], ls);
        atomicAdd(&ystats[bin*64 + 32 + c], lsq);
    }
}

// ---------------- col transform via f16 MFMA (precomputed fragments; R11 indexing) ----------------
__global__ __launch_bounds__(512) void k_colfft(uint* __restrict__ spec,
    const float* __restrict__ w1, const float* __restrict__ b1,
    const float* __restrict__ w2, const float* __restrict__ b2,
    const uint4* __restrict__ fA, const uint4* __restrict__ fB,
    const uint4* __restrict__ fG, const uint4* __restrict__ fC,
    float* __restrict__ sstats)
{
    __shared__ uint sl[32*513];
    __shared__ float wl[640];
    const int tid = threadIdx.x;
    const int lane = tid & 63, wv = tid >> 6;
    const int w = blockIdx.x, b = blockIdx.y;
    const int l15 = lane & 15, lq = lane >> 4;
    const int kb = lq * 8;

    if (tid < 128) {
        int g = tid >> 4, j = tid & 15;
        wl[g*80 + j]      = w1[g*16 + j];
        wl[g*80 + 16 + j] = w1[128 + g*16 + j];
        wl[g*80 + 32 + j] = w2[g*16 + j];
        wl[g*80 + 48 + j] = w2[128 + g*16 + j];
    } else if (tid < 160) {
        int t2 = tid - 128, g = t2 >> 2, o = t2 & 3;
        wl[g*80 + 64 + o] = b1[g*4 + o];
        wl[g*80 + 68 + o] = b1[32 + g*4 + o];
        wl[g*80 + 72 + o] = b2[g*4 + o];
        wl[g*80 + 76 + o] = b2[32 + g*4 + o];
    }
    const size_t gbase = ((size_t)b*32*WF + w) * 512;
    #pragma unroll 4
    for (int c = 0; c < 32; ++c) {
        float2 u = unpackbf(spec[gbase + (size_t)c*(WF*512) + tid]);
        sl[c*513 + tid] = packh(u.x*(1.f/512.f), u.y*(1.f/512.f));
    }
    __syncthreads();

    // ===== forward stage A (K=32)
    {
        h8 Fr[2], Fi[2], nFi[2];
        #pragma unroll
        for (int mt = 0; mt < 2; ++mt) {
            UH8 a; a.u = fA[(lane*2 + mt)*3 + 0]; Fr[mt]=a.h;
            UH8 bb; bb.u = fA[(lane*2 + mt)*3 + 1]; Fi[mt]=bb.h;
            UH8 cc; cc.u = fA[(lane*2 + mt)*3 + 2]; nFi[mt]=cc.h;
        }
        #pragma unroll
        for (int s = 0; s < 2; ++s) {
            const int n1 = wv*2 + s;
            h8 Br[2], Bi[2];
            #pragma unroll
            for (int nt = 0; nt < 2; ++nt) {
                const int base = (nt*16 + l15)*513 + n1;
                uint dd[8];
                #pragma unroll
                for (int j = 0; j < 8; ++j) dd[j] = sl[base + 16*(kb + j)];
                uint br[4], bi[4];
                #pragma unroll
                for (int p = 0; p < 4; ++p) {
                    br[p] = (dd[2*p] & 0xffffu) | (dd[2*p+1] << 16);
                    bi[p] = (dd[2*p] >> 16) | (dd[2*p+1] & 0xffff0000u);
                }
                UH8 t1_; t1_.u = make_uint4(br[0],br[1],br[2],br[3]); Br[nt]=t1_.h;
                UH8 t2_; t2_.u = make_uint4(bi[0],bi[1],bi[2],bi[3]); Bi[nt]=t2_.h;
            }
            __builtin_amdgcn_s_setprio(1);
            #pragma unroll
            for (int mt = 0; mt < 2; ++mt)
            #pragma unroll
            for (int nt = 0; nt < 2; ++nt) {
                f32x4 yr = {0.f,0.f,0.f,0.f}, yi = {0.f,0.f,0.f,0.f};
                yr = __builtin_amdgcn_mfma_f32_16x16x32_f16(Fr[mt], Br[nt], yr, 0,0,0);
                yr = __builtin_amdgcn_mfma_f32_16x16x32_f16(nFi[mt], Bi[nt], yr, 0,0,0);
                yi = __builtin_amdgcn_mfma_f32_16x16x32_f16(Fr[mt], Bi[nt], yi, 0,0,0);
                yi = __builtin_amdgcn_mfma_f32_16x16x32_f16(Fi[mt], Br[nt], yi, 0,0,0);
                const int cw = (nt*16 + l15)*513 + n1;
                #pragma unroll
                for (int r = 0; r < 4; ++r)
                    sl[cw + 16*(mt*16 + lq*4 + r)] = packh(yr[r], yi[r]);
            }
            __builtin_amdgcn_s_setprio(0);
        }
    }
    __syncthreads();

    // ===== forward stage B (K=16), k2 in [0,32)
    #pragma unroll
    for (int s = 0; s < 4; ++s) {
        const int k2 = wv*4 + s;
        h8 Ar, Ai, nAi;
        {
            UH8 a; a.u = fB[(lane*32 + k2)*3 + 0]; Ar=a.h;
            UH8 bb; bb.u = fB[(lane*32 + k2)*3 + 1]; Ai=bb.h;
            UH8 cc; cc.u = fB[(lane*32 + k2)*3 + 2]; nAi=cc.h;
        }
        #pragma unroll
        for (int ct = 0; ct < 2; ++ct) {
            const int cb2 = (ct*16 + l15)*513 + 16*k2;
            h8 Br, Bi;
            {
                uint dd[8] = {0,0,0,0,0,0,0,0};
                if (lane < 32) {
                    #pragma unroll
                    for (int j = 0; j < 8; ++j) dd[j] = sl[cb2 + kb + j];
                }
                uint br[4], bi[4];
                #pragma unroll
                for (int p = 0; p < 4; ++p) {
                    br[p] = (dd[2*p] & 0xffffu) | (dd[2*p+1] << 16);
                    bi[p] = (dd[2*p] >> 16) | (dd[2*p+1] & 0xffff0000u);
                }
                UH8 t1_; t1_.u = make_uint4(br[0],br[1],br[2],br[3]); Br=t1_.h;
                UH8 t2_; t2_.u = make_uint4(bi[0],bi[1],bi[2],bi[3]); Bi=t2_.h;
            }
            __builtin_amdgcn_s_setprio(1);
            f32x4 xr = {0.f,0.f,0.f,0.f}, xi = {0.f,0.f,0.f,0.f};
            xr = __builtin_amdgcn_mfma_f32_16x16x32_f16(Ar, Br, xr, 0,0,0);
            xr = __builtin_amdgcn_mfma_f32_16x16x32_f16(nAi, Bi, xr, 0,0,0);
            xi = __builtin_amdgcn_mfma_f32_16x16x32_f16(Ar, Bi, xi, 0,0,0);
            xi = __builtin_amdgcn_mfma_f32_16x16x32_f16(Ai, Br, xi, 0,0,0);
            __builtin_amdgcn_s_setprio(0);
            #pragma unroll
            for (int r = 0; r < 4; ++r)
                sl[cb2 + lq*4 + r] = packh(xr[r], xi[r]);
        }
    }
    __syncthreads();

    // ===== MLP + softshrink + gate (pointwise)
    #pragma unroll
    for (int g = 0; g < 8; ++g) {
        const float* wk = wl + g*80;
        float xr[4], xi[4];
        #pragma unroll
        for (int i = 0; i < 4; ++i) {
            float2 v = unph(sl[(4*g+i)*513 + tid]);
            xr[i] = v.x; xi[i] = v.y;
        }
        float o1r[4], o1i[4];
        #pragma unroll
        for (int o = 0; o < 4; ++o) {
            float sr = wk[64+o], si = wk[68+o];
            #pragma unroll
            for (int i = 0; i < 4; ++i) {
                float wr = wk[i*4+o], wi = wk[16 + i*4+o];
                sr += xr[i]*wr - xi[i]*wi;
                si += xi[i]*wr + xr[i]*wi;
            }
            o1r[o] = fmaxf(sr, 0.f);
            o1i[o] = fmaxf(si, 0.f);
        }
        #pragma unroll
        for (int o = 0; o < 4; ++o) {
            float sr = wk[72+o], si = wk[76+o];
            #pragma unroll
            for (int i = 0; i < 4; ++i) {
                float wr = wk[32 + i*4+o], wi = wk[48 + i*4+o];
                sr += o1r[i]*wr - o1i[i]*wi;
                si += o1i[i]*wr + o1r[i]*wi;
            }
            sr = (sr > LAM) ? sr - LAM : ((sr < -LAM) ? sr + LAM : 0.f);
            si = (si > LAM) ? si - LAM : ((si < -LAM) ? si + LAM : 0.f);
            sl[(4*g+o)*513 + tid] = packh(sr*xr[o] - si*xi[o], sr*xi[o] + si*xr[o]);
        }
    }
    __syncthreads();

    // ===== inverse stage 1 (K=16)
    {
        h8 Gr, Gi, nGi;
        {
            UH8 a; a.u = fG[lane*3 + 0]; Gr=a.h;
            UH8 bb; bb.u = fG[lane*3 + 1]; Gi=bb.h;
            UH8 cc; cc.u = fG[lane*3 + 2]; nGi=cc.h;
        }
        #pragma unroll
        for (int s = 0; s < 4; ++s) {
            const int k2 = wv*4 + s;
            #pragma unroll
            for (int ct = 0; ct < 2; ++ct) {
                const int cb2 = (ct*16 + l15)*513 + 16*k2;
                h8 Br, Bi;
                {
                    uint dd[8] = {0,0,0,0,0,0,0,0};
                    if (lane < 32) {
                        #pragma unroll
                        for (int j = 0; j < 8; ++j) dd[j] = sl[cb2 + kb + j];
                    }
                    uint br[4], bi[4];
                    #pragma unroll
                    for (int p = 0; p < 4; ++p) {
                        br[p] = (dd[2*p] & 0xffffu) | (dd[2*p+1] << 16);
                        bi[p] = (dd[2*p] >> 16) | (dd[2*p+1] & 0xffff0000u);
                    }
                    UH8 t1_; t1_.u = make_uint4(br[0],br[1],br[2],br[3]); Br=t1_.h;
                    UH8 t2_; t2_.u = make_uint4(bi[0],bi[1],bi[2],bi[3]); Bi=t2_.h;
                }
                __builtin_amdgcn_s_setprio(1);
                f32x4 yr = {0.f,0.f,0.f,0.f}, yi = {0.f,0.f,0.f,0.f};
                yr = __builtin_amdgcn_mfma_f32_16x16x32_f16(Gr, Br, yr, 0,0,0);
                yr = __builtin_amdgcn_mfma_f32_16x16x32_f16(nGi, Bi, yr, 0,0,0);
                yi = __builtin_amdgcn_mfma_f32_16x16x32_f16(Gr, Bi, yi, 0,0,0);
                yi = __builtin_amdgcn_mfma_f32_16x16x32_f16(Gi, Br, yi, 0,0,0);
                __builtin_amdgcn_s_setprio(0);
                #pragma unroll
                for (int r = 0; r < 4; ++r)
                    sl[cb2 + lq*4 + r] = packh(yr[r], yi[r]);
            }
        }
    }
    __syncthreads();

    // ===== inverse stage 2 (K=32)
    #pragma unroll
    for (int s = 0; s < 2; ++s) {
        const int n1 = wv*2 + s;
        h8 Cr[2], Ci[2], nCi[2];
        #pragma unroll
        for (int mt = 0; mt < 2; ++mt) {
            UH8 a; a.u = fC[((lane*16 + n1)*2 + mt)*3 + 0]; Cr[mt]=a.h;
            UH8 bb; bb.u = fC[((lane*16 + n1)*2 + mt)*3 + 1]; Ci[mt]=bb.h;
            UH8 cc; cc.u = fC[((lane*16 + n1)*2 + mt)*3 + 2]; nCi[mt]=cc.h;
        }
        h8 Br[2], Bi[2];
        #pragma unroll
        for (int nt = 0; nt < 2; ++nt) {
            const int base = (nt*16 + l15)*513 + n1;
            uint dd[8];
            #pragma unroll
            for (int j = 0; j < 8; ++j) dd[j] = sl[base + 16*(kb + j)];
            uint br[4], bi[4];
            #pragma unroll
            for (int p = 0; p < 4; ++p) {
                br[p] = (dd[2*p] & 0xffffu) | (dd[2*p+1] << 16);
                bi[p] = (dd[2*p] >> 16) | (dd[2*p+1] & 0xffff0000u);
            }
            UH8 t1_; t1_.u = make_uint4(br[0],br[1],br[2],br[3]); Br[nt]=t1_.h;
            UH8 t2_; t2_.u = make_uint4(bi[0],bi[1],bi[2],bi[3]); Bi[nt]=t2_.h;
        }
        __builtin_amdgcn_s_setprio(1);
        #pragma unroll
        for (int mt = 0; mt < 2; ++mt)
        #pragma unroll
        for (int nt = 0; nt < 2; ++nt) {
            f32x4 xr = {0.f,0.f,0.f,0.f}, xi = {0.f,0.f,0.f,0.f};
            xr = __builtin_amdgcn_mfma_f32_16x16x32_f16(Cr[mt], Br[nt], xr, 0,0,0);
            xr = __builtin_amdgcn_mfma_f32_16x16x32_f16(nCi[mt], Bi[nt], xr, 0,0,0);
            xi = __builtin_amdgcn_mfma_f32_16x16x32_f16(Cr[mt], Bi[nt], xi, 0,0,0);
            xi = __builtin_amdgcn_mfma_f32_16x16x32_f16(Ci[mt], Br[nt], xi, 0,0,0);
            const int cw = (nt*16 + l15)*513 + n1;
            #pragma unroll
            for (int r = 0; r < 4; ++r)
                sl[cw + 16*(mt*16 + lq*4 + r)] = packh(xr[r], xi[r]);
        }
        __builtin_amdgcn_s_setprio(0);
    }
    __syncthreads();

    // ===== epilogue: bf16 write-back + Parseval sums
    const bool edge = (w == 0) || (w == 256);
    #pragma unroll
    for (int i = 0; i < 4; ++i) {
        const int c = wv*4 + i;
        const size_t cb = gbase + (size_t)c*(WF*512);
        float fgg = 0.f, fgu = 0.f, fg0 = 0.f;
        #pragma unroll
        for (int it = 0; it < 4; ++it) {
            const int pos = it*128 + 2*lane;
            uint2 dv;
            dv.x = sl[c*513 + pos];
            dv.y = sl[c*513 + pos + 1];
            float2 z0 = unph(dv.x), z1 = unph(dv.y);
            uint2 up = *(const uint2*)(spec + cb + pos);
            float2 u0 = unpackbf(up.x), u1 = unpackbf(up.y);
            uint2 gp;
            gp.x = packbf(z0.x, z0.y);
            gp.y = packbf(z1.x, z1.y);
            *(uint2*)(spec + cb + pos) = gp;
            float2 g0 = unpackbf(gp.x), g1 = unpackbf(gp.y);
            if (edge) {
                fgg += g0.x*g0.x + g1.x*g1.x;
                fgu += g0.x*u0.x + g1.x*u1.x;
                if (w == 0) fg0 += g0.x + g1.x;
            } else {
                fgg += 2.f*(g0.x*g0.x + g0.y*g0.y + g1.x*g1.x + g1.y*g1.y);
                fgu += 2.f*(g0.x*u0.x + g0.y*u0.y + g1.x*u1.x + g1.y*u1.y);
            }
        }
        #pragma unroll
        for (int off = 32; off; off >>= 1){
            fgg += __shfl_down(fgg, off, 64);
            fgu += __shfl_down(fgu, off, 64);
            fg0 += __shfl_down(fg0, off, 64);
        }
        if (lane == 0) {
            const int kk = c >> 2, ch = c & 3;
            const int bin = (w + b*8 + kk) & 31;
            atomicAdd(&sstats[bin*96 + kk*4 + ch], fgg);
            atomicAdd(&sstats[bin*96 + 32 + kk*4 + ch], fgu);
            if (w == 0) atomicAdd(&sstats[bin*96 + 64 + kk*4 + ch], fg0);
        }
    }
}

// ---------------- row irfft: wave-local inverse FFT + BN2 + final ReLU ----------------
__global__ __launch_bounds__(512) void k_rowfft_inv(
    const uint* __restrict__ spec, const ushort* __restrict__ cvo,
    const float* __restrict__ bnp, const float* __restrict__ bnp2,
    const float2* __restrict__ twg, float* __restrict__ out)
{
    __shared__ float2 tw[512];
    __shared__ uint d[8*ROWH];
    const int tid = threadIdx.x;
    const int h0 = blockIdx.x * 16;
    const int bc = blockIdx.y;
    const int c = bc & 31;
    ld_tw<512>(tw, twg, tid);
    for (int i = tid; i < 8*WF; i += 512) {
        int p = i & 7, w = i >> 3;
        uint2 pk = *(const uint2*)(spec + ((size_t)bc*WF + w)*512 + h0 + 2*p);
        float2 X1 = unpackbf(pk.x), X2 = unpackbf(pk.y);
        if (w == 0 || w == 256) { X1.y = 0.f; X2.y = 0.f; }
        const float s = 1.f/512.f;
        d[p*ROWH + LPH(w)] = packh((X1.x - X2.y)*s, (X1.y + X2.x)*s);
        if ((unsigned)(w - 1) < 255u)
            d[p*ROWH + LPH(512 - w)] = packh((X1.x + X2.y)*s, (X2.x - X1.y)*s);
    }
    __syncthreads();
    const int row = tid >> 6, l = tid & 63;
    const int o0 = ((l&7)<<3) | (l>>3);
    uint* drow = d + row*ROWH;
    {
        float2 v[8];
        oct_gather(drow, o0, v);
        dft8<true>(v);
        WSYNC();
        oct_write(drow, l, v);
    }
    fft_wave12<true>(drow, tw, l);
    const float s1 = bnp[c],  t1 = bnp[32+c];
    const float s2 = bnp2[c], t2 = bnp2[32+c];
    const size_t gbase = ((size_t)bc*512 + h0 + 2*row)*512;
    #pragma unroll
    for (int q = 0; q < 8; ++q) {
        const int col = q*64 + l;
        float2 v = unph(drow[LPH(col)]);
        float y0 = fmaxf(fmaf(bf2f(cvo[gbase + col]), s1, t1), 0.f);
        float fo0 = v.x + y0;
        out[gbase + col] = fmaxf(y0 + fmaf(fo0, s2, t2), 0.f);
        float y1 = fmaxf(fmaf(bf2f(cvo[gbase + 512 + col]), s1, t1), 0.f);
        float fo1 = v.y + y1;
        out[gbase + 512 + col] = fmaxf(y1 + fmaf(fo1, s2, t2), 0.f);
    }
}

extern "C" void kernel_launch(void* const* d_in, const int* in_sizes, int n_in,
                              void* d_out, int out_size, void* d_ws, size_t ws_size,
                              hipStream_t stream)
{
    const float* x      = (const float*)d_in[0];
    const float* conv_w = (const float*)d_in[1];
    const float* conv_b = (const float*)d_in[2];
    const float* bn1g   = (const float*)d_in[3];
    const float* bn1b   = (const float*)d_in[4];
    const float* w1     = (const float*)d_in[5];
    const float* b1     = (const float*)d_in[6];
    const float* w2     = (const float*)d_in[7];
    const float* b2     = (const float*)d_in[8];
    const float* bn2g   = (const float*)d_in[9];
    const float* bn2b   = (const float*)d_in[10];
    float* out = (float*)d_out;

    char* ws = (char*)d_ws;
    uint*   spec  = (uint*)ws;                              // 67,371,008 B (bf16 pairs)
    ushort* xt    = (ushort*)ws;                            // aliases spec (dead before spec written)
    ushort* cvo   = (ushort*)(ws + 67371008);               // 67,108,864 B (bf16)
    ushort* wtp   = (ushort*)(ws + 67371008 + 67108864);    // 18,432 B
    float*  stats = (float*)(ws + 67371008 + 67108864 + 18432);
    float* stats1 = stats;             // 4096 f (bn1 bins)
    float* ystats = stats + 4096;      // 4096 f
    float* sstats = stats + 8192;      // 3072 f
    float* bnp1   = stats + 11264;     // 64 f
    float* bnp2   = stats + 11328;     // 64 f
    float2* twg   = (float2*)(stats + 11392); // 512 float2 (ends at stats+12416)
    uint4* fA = (uint4*)(stats + 12416);      // 384 uint4
    uint4* fB = fA + 384;                     // 6144 uint4 (64 lanes x 32 k2 x 3)
    uint4* fG = fB + 6144;                    // 192 uint4
    uint4* fC = fG + 192;                     // 6144 uint4

    (void)hipMemsetAsync(stats, 0, 11264*sizeof(float), stream);
    k_twiddle<<<2, 256, 0, stream>>>(twg);
    k_mfrag<<<67, 64, 0, stream>>>(fA, fB, fG, fC);
    k_wprep<<<36, 256, 0, stream>>>(conv_w, wtp);
    k_transpose<<<dim3(8,512,4), 256, 0, stream>>>(x, xt);
    k_conv_mfma<<<dim3(8,128,4), 256, 0, stream>>>(xt, wtp, conv_b, cvo, stats1);
    k_finalize<<<1, 64, 0, stream>>>(stats1, 64, bn1g, bn1b, bnp1);
    k_rowfft_fwd<<<dim3(32,128), 512, 0, stream>>>(cvo, bnp1, twg, spec, ystats);
    k_colfft<<<dim3(257,4), 512, 0, stream>>>(spec, w1, b1, w2, b2, fA, fB, fG, fC, sstats);
    k_finalize2<<<1, 64, 0, stream>>>(ystats, sstats, bn2g, bn2b, bnp2);
    k_rowfft_inv<<<dim3(32,128), 512, 0, stream>>>(spec, cvo, bnp1, bnp2, twg, out);
}